// Round 1
// baseline (1179.385 us; speedup 1.0000x reference)
//
#include <hip/hip_runtime.h>

// Problem constants (fixed by reference)
#define NB    2          // batch
#define NC    256        // channels
#define NH    64
#define NW    64
#define NKF   12         // num gaussian kernels
#define NROI  256        // B*R
#define HID   4096
#define INDIM 12544      // 256*49
#define KCH   8          // split-K chunks for GEMM1
#define KCLEN 1568       // 12544/8

typedef __attribute__((ext_vector_type(8))) short short8;
typedef __attribute__((ext_vector_type(4))) float floatx4;

__device__ __forceinline__ unsigned short f2bf(float f) {
  unsigned int u = __float_as_uint(f);
  u += 0x7fffu + ((u >> 16) & 1u);   // round-to-nearest-even
  return (unsigned short)(u >> 16);
}
__device__ __forceinline__ float bf2f(unsigned short s) {
  return __uint_as_float(((unsigned int)s) << 16);
}

// ---------------------------------------------------------------------------
// 1) base_feat [B,C,H,W] -> featT [B,H,W,C]  (channels-last, fp32)
__global__ void k_transpose(const float* __restrict__ base, float* __restrict__ featT) {
  int bid = blockIdx.x;            // B*H = 128
  int b = bid >> 6, y = bid & 63;
  __shared__ float tile[64][65];
  for (int cc = 0; cc < 4; ++cc) {
    int c0 = cc * 64;
    #pragma unroll
    for (int i = 0; i < 16; ++i) {
      int idx = threadIdx.x + i * 256;
      int ci = idx >> 6, xi = idx & 63;
      tile[ci][xi] = base[(((b * NC) + c0 + ci) * NH + y) * NW + xi];
    }
    __syncthreads();
    #pragma unroll
    for (int i = 0; i < 16; ++i) {
      int idx = threadIdx.x + i * 256;
      int xo = idx >> 6, co = idx & 63;
      featT[((b * NH + y) * NW + xo) * NC + c0 + co] = tile[co][xo];
    }
    __syncthreads();
  }
}

// ---------------------------------------------------------------------------
// 2) depthwise 7x7 gaussian conv, all 12 kernels fused, channels-last bf16 out
//    filteredT [NKF, B, H, W, C]
__global__ void k_conv(const float* __restrict__ featT, const float* __restrict__ kern,
                       unsigned short* __restrict__ filteredT) {
  int bid = blockIdx.x;            // B*H*(W/16) = 512
  int xb = bid & 3;
  int y  = (bid >> 2) & 63;
  int b  = bid >> 8;
  int c  = threadIdx.x;            // 256 channels
  int x0 = xb * 16;
  for (int x = x0; x < x0 + 16; ++x) {
    float acc[NKF];
    #pragma unroll
    for (int k = 0; k < NKF; ++k) acc[k] = 0.f;
    #pragma unroll
    for (int dy = 0; dy < 7; ++dy) {
      int yy = y + dy - 3;
      if (yy < 0 || yy >= NH) continue;     // zero pad (uniform branch)
      #pragma unroll
      for (int dx = 0; dx < 7; ++dx) {
        int xx = x + dx - 3;
        if (xx < 0 || xx >= NW) continue;
        float v = featT[((b * NH + yy) * NW + xx) * NC + c];
        #pragma unroll
        for (int k = 0; k < NKF; ++k)
          acc[k] += v * kern[k * (NC * 49) + dy * 7 + dx];  // kernel[k,0,0,dy,dx], uniform -> s_load
      }
    }
    #pragma unroll
    for (int k = 0; k < NKF; ++k)
      filteredT[(((k * NB + b) * NH + y) * NW + x) * NC + c] = f2bf(acc[k]);
  }
}

// ---------------------------------------------------------------------------
// 3) RoIAlignAvg of base -> MLP input x [NROI, 12544] bf16 (c-major, 7x7 minor)
__global__ void k_roi_base(const float* __restrict__ featT, const float* __restrict__ rois,
                           unsigned short* __restrict__ xbf) {
  int n = blockIdx.x;
  int c = threadIdx.x;
  const float* r = rois + n * 5;
  int b = (int)r[0];
  float x1 = r[1] * 0.0625f, y1 = r[2] * 0.0625f;
  float x2 = r[3] * 0.0625f, y2 = r[4] * 0.0625f;
  const float* fb = featT + (size_t)b * (NH * NW * NC) + c;
  float pacc[49];
  #pragma unroll
  for (int i = 0; i < 49; ++i) pacc[i] = 0.f;
  #pragma unroll
  for (int gy = 0; gy < 8; ++gy) {
    float ys = y1 + (y2 - y1) * (gy * (1.f / 7.f));
    ys = fminf(fmaxf(ys, 0.f), 63.f);
    float yf = floorf(ys);
    int iy0 = (int)yf, iy1 = min(iy0 + 1, 63);
    float wyg = ys - yf;
    #pragma unroll
    for (int gx = 0; gx < 8; ++gx) {
      float xs = x1 + (x2 - x1) * (gx * (1.f / 7.f));
      xs = fminf(fmaxf(xs, 0.f), 63.f);
      float xf = floorf(xs);
      int ix0 = (int)xf, ix1 = min(ix0 + 1, 63);
      float wxg = xs - xf;
      float v00 = fb[(iy0 * NW + ix0) * NC];
      float v01 = fb[(iy0 * NW + ix1) * NC];
      float v10 = fb[(iy1 * NW + ix0) * NC];
      float v11 = fb[(iy1 * NW + ix1) * NC];
      float top = v00 + (v01 - v00) * wxg;
      float bot = v10 + (v11 - v10) * wxg;
      float crop = top + (bot - top) * wyg;
      #pragma unroll
      for (int p = gy - 1; p <= gy; ++p) {
        if (p < 0 || p > 6) continue;
        #pragma unroll
        for (int q = gx - 1; q <= gx; ++q) {
          if (q < 0 || q > 6) continue;
          pacc[p * 7 + q] += crop;           // 2x2 avg-pool accumulation
        }
      }
    }
  }
  unsigned short* xp = xbf + (size_t)n * INDIM + c * 49;
  #pragma unroll
  for (int pq = 0; pq < 49; ++pq) xp[pq] = f2bf(0.25f * pacc[pq]);
}

// ---------------------------------------------------------------------------
// 4) GEMM1: h_partial = x @ W1^T, split-K. M=256 full (W1 read once from HBM).
//    grid (64 n-tiles, 8 k-chunks), 256 threads. bf16 MFMA 16x16x32.
__global__ void __launch_bounds__(256) k_gemm1(const unsigned short* __restrict__ A,
                                               const float* __restrict__ W1,
                                               float* __restrict__ partial) {
  __shared__ unsigned short As[256 * 40];   // 256 x 32, pad to 40 (bank spread)
  __shared__ unsigned short Bs[64 * 40];
  int nb = blockIdx.x, kc = blockIdx.y;
  int j0 = nb * 64;
  int kbase = kc * KCLEN;
  int tid = threadIdx.x;
  int wv = tid >> 6, lane = tid & 63;
  int quad = lane >> 4, l15 = lane & 15;
  int m0 = wv * 64;                          // wave -> 64 M-rows
  floatx4 acc[4][4];
  #pragma unroll
  for (int i = 0; i < 4; ++i)
    #pragma unroll
    for (int j = 0; j < 4; ++j) acc[i][j] = (floatx4)0.0f;

  for (int ks = 0; ks < KCLEN / 32; ++ks) {  // 49 steps
    int kk = kbase + ks * 32;
    // stage A: 256 rows x 32 k bf16 (1024 x 16B chunks)
    #pragma unroll
    for (int rr = 0; rr < 4; ++rr) {
      int q = tid + rr * 256;
      int row = q >> 2, part = q & 3;
      short8 av = *(const short8*)(A + (size_t)row * INDIM + kk + part * 8);
      *(short8*)(As + row * 40 + part * 8) = av;
    }
    // stage B: 64 rows (j) x 32 k, fp32 -> bf16 convert on the fly
    #pragma unroll
    for (int rr = 0; rr < 2; ++rr) {
      int q = tid + rr * 256;
      int row = q >> 3, part = q & 7;
      floatx4 bv = *(const floatx4*)(W1 + (size_t)(j0 + row) * INDIM + kk + part * 4);
      union { unsigned short us[4]; unsigned long long u; } cv;
      cv.us[0] = f2bf(bv.x); cv.us[1] = f2bf(bv.y);
      cv.us[2] = f2bf(bv.z); cv.us[3] = f2bf(bv.w);
      *(unsigned long long*)(Bs + row * 40 + part * 4) = cv.u;
    }
    __syncthreads();
    short8 af[4];
    #pragma unroll
    for (int mi = 0; mi < 4; ++mi)   // A frag: A[m=lane&15][k=quad*8+i]
      af[mi] = *(const short8*)(As + (m0 + mi * 16 + l15) * 40 + quad * 8);
    #pragma unroll
    for (int ni = 0; ni < 4; ++ni) { // B frag: B[k=quad*8+i][n=lane&15]
      short8 bfv = *(const short8*)(Bs + (ni * 16 + l15) * 40 + quad * 8);
      #pragma unroll
      for (int mi = 0; mi < 4; ++mi)
        acc[mi][ni] = __builtin_amdgcn_mfma_f32_16x16x32_bf16(af[mi], bfv, acc[mi][ni], 0, 0, 0);
    }
    __syncthreads();
  }
  // epilogue: D[row=quad*4+r][col=lane&15]
  float* po = partial + (size_t)kc * (NROI * HID);
  #pragma unroll
  for (int mi = 0; mi < 4; ++mi) {
    #pragma unroll
    for (int ni = 0; ni < 4; ++ni) {
      int j = j0 + ni * 16 + l15;
      #pragma unroll
      for (int rg = 0; rg < 4; ++rg) {
        int m = m0 + mi * 16 + quad * 4 + rg;
        po[(size_t)m * HID + j] = acc[mi][ni][rg];
      }
    }
  }
}

// ---------------------------------------------------------------------------
// 5) reduce split-K partials + bias + BN + ReLU -> h bf16 [NROI, HID]
__global__ void k_reduce(const float* __restrict__ partial, const float* __restrict__ b1,
                         const float* __restrict__ g1, const float* __restrict__ be1,
                         const float* __restrict__ m1, const float* __restrict__ v1,
                         unsigned short* __restrict__ h) {
  int idx = blockIdx.x * 256 + threadIdx.x;   // NROI*HID = 1048576
  int j = idx & (HID - 1);
  float s = 0.f;
  #pragma unroll
  for (int kc = 0; kc < KCH; ++kc) s += partial[kc * (NROI * HID) + idx];
  s += b1[j];
  s = (s - m1[j]) * rsqrtf(v1[j] + 1e-5f) * g1[j] + be1[j];
  s = fmaxf(s, 0.f);
  h[idx] = f2bf(s);
}

// ---------------------------------------------------------------------------
// 6) head: o = h @ W2^T + b2, BN, softmax over 12 -> wgt [NROI, 12] fp32
__global__ void k_head(const unsigned short* __restrict__ h, const float* __restrict__ W2,
                       const float* __restrict__ b2, const float* __restrict__ g2,
                       const float* __restrict__ be2, const float* __restrict__ m2,
                       const float* __restrict__ v2, float* __restrict__ wgt) {
  int n = blockIdx.x;
  int tid = threadIdx.x;
  float p[NKF];
  #pragma unroll
  for (int j = 0; j < NKF; ++j) p[j] = 0.f;
  for (int k = tid; k < HID; k += 256) {
    float hv = bf2f(h[n * HID + k]);
    #pragma unroll
    for (int j = 0; j < NKF; ++j) p[j] += hv * W2[j * HID + k];
  }
  #pragma unroll
  for (int j = 0; j < NKF; ++j) {
    #pragma unroll
    for (int off = 32; off > 0; off >>= 1) p[j] += __shfl_down(p[j], off, 64);
  }
  __shared__ float red[4][NKF];
  int wv = tid >> 6, lane = tid & 63;
  if (lane == 0) {
    #pragma unroll
    for (int j = 0; j < NKF; ++j) red[wv][j] = p[j];
  }
  __syncthreads();
  if (tid == 0) {
    float o[NKF], mx = -1e30f;
    #pragma unroll
    for (int j = 0; j < NKF; ++j) {
      float t = red[0][j] + red[1][j] + red[2][j] + red[3][j] + b2[j];
      t = (t - m2[j]) * rsqrtf(v2[j] + 1e-5f) * g2[j] + be2[j];
      o[j] = t;
      mx = fmaxf(mx, t);
    }
    float s = 0.f;
    #pragma unroll
    for (int j = 0; j < NKF; ++j) { o[j] = __expf(o[j] - mx); s += o[j]; }
    float inv = 1.f / s;
    #pragma unroll
    for (int j = 0; j < NKF; ++j) wgt[n * NKF + j] = o[j] * inv;
  }
}

// ---------------------------------------------------------------------------
// 7) final: out[n,c,7,7] = sum_k wgt[n,k] * RoIAlignAvg(filtered_k)[n,c]
//    grid (NROI, 4), 64 threads (one channel quarter per block)
__global__ void k_final(const unsigned short* __restrict__ filteredT,
                        const float* __restrict__ rois, const float* __restrict__ wgt,
                        float* __restrict__ out) {
  int n = blockIdx.x;
  int c = blockIdx.y * 64 + threadIdx.x;
  const float* r = rois + n * 5;
  int b = (int)r[0];
  float x1 = r[1] * 0.0625f, y1 = r[2] * 0.0625f;
  float x2 = r[3] * 0.0625f, y2 = r[4] * 0.0625f;
  int ix0[8], ix1[8], iy0[8], iy1[8];
  float wx[8], wy[8];
  #pragma unroll
  for (int g = 0; g < 8; ++g) {
    float xs = x1 + (x2 - x1) * (g * (1.f / 7.f));
    xs = fminf(fmaxf(xs, 0.f), 63.f);
    float xf = floorf(xs);
    ix0[g] = (int)xf; ix1[g] = min(ix0[g] + 1, 63); wx[g] = xs - xf;
    float ys = y1 + (y2 - y1) * (g * (1.f / 7.f));
    ys = fminf(fmaxf(ys, 0.f), 63.f);
    float yf = floorf(ys);
    iy0[g] = (int)yf; iy1[g] = min(iy0[g] + 1, 63); wy[g] = ys - yf;
  }
  float acc[64];
  #pragma unroll
  for (int i = 0; i < 64; ++i) acc[i] = 0.f;
  for (int k = 0; k < NKF; ++k) {
    float wk = wgt[n * NKF + k];
    const unsigned short* fk = filteredT + ((size_t)(k * NB + b)) * (NH * NW * NC) + c;
    #pragma unroll
    for (int gy = 0; gy < 8; ++gy) {
      int r0 = iy0[gy] * (NW * NC), r1 = iy1[gy] * (NW * NC);
      float wyg = wy[gy];
      #pragma unroll
      for (int gx = 0; gx < 8; ++gx) {
        int c0 = ix0[gx] * NC, c1 = ix1[gx] * NC;
        float v00 = bf2f(fk[r0 + c0]);
        float v01 = bf2f(fk[r0 + c1]);
        float v10 = bf2f(fk[r1 + c0]);
        float v11 = bf2f(fk[r1 + c1]);
        float top = v00 + (v01 - v00) * wx[gx];
        float bot = v10 + (v11 - v10) * wx[gx];
        acc[gy * 8 + gx] += wk * (top + (bot - top) * wyg);
      }
    }
  }
  float* op = out + ((size_t)n * NC + c) * 49;
  #pragma unroll
  for (int p = 0; p < 7; ++p)
    #pragma unroll
    for (int q = 0; q < 7; ++q)
      op[p * 7 + q] = 0.25f * (acc[p * 8 + q] + acc[p * 8 + q + 1]
                               + acc[p * 8 + q + 8] + acc[p * 8 + q + 9]);
}

// ---------------------------------------------------------------------------
extern "C" void kernel_launch(void* const* d_in, const int* in_sizes, int n_in,
                              void* d_out, int out_size, void* d_ws, size_t ws_size,
                              hipStream_t stream) {
  const float* base = (const float*)d_in[0];
  const float* kern = (const float*)d_in[1];
  const float* rois = (const float*)d_in[2];
  const float* W1  = (const float*)d_in[3];
  const float* b1  = (const float*)d_in[4];
  const float* g1  = (const float*)d_in[5];
  const float* be1 = (const float*)d_in[6];
  const float* m1  = (const float*)d_in[7];
  const float* v1  = (const float*)d_in[8];
  const float* W2  = (const float*)d_in[9];
  const float* b2  = (const float*)d_in[10];
  const float* g2  = (const float*)d_in[11];
  const float* be2 = (const float*)d_in[12];
  const float* m2  = (const float*)d_in[13];
  const float* v2  = (const float*)d_in[14];
  float* out = (float*)d_out;

  // workspace layout (≈96.1 MiB total)
  char* ws = (char*)d_ws;
  float*          featT     = (float*)(ws);                    //  8 MiB  [B,H,W,C] fp32
  unsigned short* filteredT = (unsigned short*)(ws + 8388608); // 48 MiB  [12,B,H,W,C] bf16
  unsigned short* xbf       = (unsigned short*)(ws + 58720256);//  6.1 MiB [NROI, 12544] bf16
  float*          partial   = (float*)(ws + 65142784);         // 32 MiB  [8, NROI, HID] fp32
  unsigned short* hbf       = (unsigned short*)(ws + 98697216);//  2 MiB  [NROI, HID] bf16
  float*          wgt       = (float*)(ws + 100794368);        // 12 KiB  [NROI, 12] fp32

  hipLaunchKernelGGL(k_transpose, dim3(NB * NH), dim3(256), 0, stream, base, featT);
  hipLaunchKernelGGL(k_conv, dim3(NB * NH * 4), dim3(256), 0, stream, featT, kern, filteredT);
  hipLaunchKernelGGL(k_roi_base, dim3(NROI), dim3(256), 0, stream, featT, rois, xbf);
  hipLaunchKernelGGL(k_gemm1, dim3(64, KCH), dim3(256), 0, stream, xbf, W1, partial);
  hipLaunchKernelGGL(k_reduce, dim3(NROI * HID / 256), dim3(256), 0, stream,
                     partial, b1, g1, be1, m1, v1, hbf);
  hipLaunchKernelGGL(k_head, dim3(NROI), dim3(256), 0, stream, hbf, W2, b2, g2, be2, m2, v2, wgt);
  hipLaunchKernelGGL(k_final, dim3(NROI, 4), dim3(64), 0, stream, filteredT, rois, wgt, out);
}

// Round 2
// 898.581 us; speedup vs baseline: 1.3125x; 1.3125x over previous
//
#include <hip/hip_runtime.h>

// Problem constants (fixed by reference)
#define NB    2          // batch
#define NC    256        // channels
#define NH    64
#define NW    64
#define NKF   12         // num gaussian kernels
#define NROI  256        // B*R
#define HID   4096
#define INDIM 12544      // 256*49
#define KCH   8          // split-K chunks for GEMM1
#define KCLEN 1568       // 12544/8

typedef __attribute__((ext_vector_type(8))) short short8;
typedef __attribute__((ext_vector_type(4))) short short4v;
typedef __attribute__((ext_vector_type(4))) float floatx4;

__device__ __forceinline__ unsigned short f2bf(float f) {
  unsigned int u = __float_as_uint(f);
  u += 0x7fffu + ((u >> 16) & 1u);   // round-to-nearest-even
  return (unsigned short)(u >> 16);
}
__device__ __forceinline__ float bf2f(unsigned short s) {
  return __uint_as_float(((unsigned int)s) << 16);
}

// ---------------------------------------------------------------------------
// 1) base_feat [B,C,H,W] -> featT [B,H,W,C]  (channels-last, fp32)
__global__ void k_transpose(const float* __restrict__ base, float* __restrict__ featT) {
  int bid = blockIdx.x;            // B*H = 128
  int b = bid >> 6, y = bid & 63;
  __shared__ float tile[64][65];
  for (int cc = 0; cc < 4; ++cc) {
    int c0 = cc * 64;
    #pragma unroll
    for (int i = 0; i < 16; ++i) {
      int idx = threadIdx.x + i * 256;
      int ci = idx >> 6, xi = idx & 63;
      tile[ci][xi] = base[(((b * NC) + c0 + ci) * NH + y) * NW + xi];
    }
    __syncthreads();
    #pragma unroll
    for (int i = 0; i < 16; ++i) {
      int idx = threadIdx.x + i * 256;
      int xo = idx >> 6, co = idx & 63;
      featT[((b * NH + y) * NW + xo) * NC + c0 + co] = tile[co][xo];
    }
    __syncthreads();
  }
}

// ---------------------------------------------------------------------------
// 2) depthwise 7x7 gaussian conv, all 12 kernels fused.
//    NEW layout: filteredT [B,H,W,C,NKF] bf16 (k innermost -> short4 gathers later)
__global__ void k_conv(const float* __restrict__ featT, const float* __restrict__ kern,
                       unsigned short* __restrict__ filteredT) {
  int bid = blockIdx.x;            // B*H*(W/16) = 512
  int xb = bid & 3;
  int y  = (bid >> 2) & 63;
  int b  = bid >> 8;
  int c  = threadIdx.x;            // 256 channels
  int x0 = xb * 16;
  for (int x = x0; x < x0 + 16; ++x) {
    float acc[NKF];
    #pragma unroll
    for (int k = 0; k < NKF; ++k) acc[k] = 0.f;
    #pragma unroll
    for (int dy = 0; dy < 7; ++dy) {
      int yy = y + dy - 3;
      if (yy < 0 || yy >= NH) continue;     // zero pad (uniform branch)
      #pragma unroll
      for (int dx = 0; dx < 7; ++dx) {
        int xx = x + dx - 3;
        if (xx < 0 || xx >= NW) continue;
        float v = featT[((b * NH + yy) * NW + xx) * NC + c];
        #pragma unroll
        for (int k = 0; k < NKF; ++k)
          acc[k] += v * kern[k * (NC * 49) + dy * 7 + dx];  // uniform -> s_load
      }
    }
    short4v s[3];
    #pragma unroll
    for (int m = 0; m < 3; ++m)
      #pragma unroll
      for (int j = 0; j < 4; ++j) s[m][j] = (short)f2bf(acc[m * 4 + j]);
    unsigned short* dst = filteredT + ((size_t)(((b * NH + y) * NW + x) * NC + c)) * NKF;
    *(short4v*)(dst)     = s[0];
    *(short4v*)(dst + 4) = s[1];
    *(short4v*)(dst + 8) = s[2];
  }
}

// ---------------------------------------------------------------------------
// shared roi geometry helper
struct RoiGeom {
  int b;
  float x1, y1, x2, y2;
};
__device__ __forceinline__ RoiGeom roi_geom(const float* __restrict__ rois, int n) {
  const float* r = rois + n * 5;
  RoiGeom g;
  g.b = (int)r[0];
  g.x1 = r[1] * 0.0625f; g.y1 = r[2] * 0.0625f;
  g.x2 = r[3] * 0.0625f; g.y2 = r[4] * 0.0625f;
  return g;
}

// ---------------------------------------------------------------------------
// 3) RoIAlignAvg of base -> MLP input x [NROI, 12544] bf16 (c-major, 7x7 minor)
//    quadrant-split over pool output for occupancy
template<int GY0, int GYN, int P0, int PN, int GX0, int GXN, int Q0, int QN>
__device__ __forceinline__ void roi_base_quad(const float* __restrict__ featT,
                                              const float* __restrict__ rois,
                                              unsigned short* __restrict__ xbf,
                                              int n, int c) {
  RoiGeom g = roi_geom(rois, n);
  int ix0[GXN], ix1[GXN], iy0[GYN], iy1[GYN];
  float wx[GXN], wy[GYN];
  #pragma unroll
  for (int i = 0; i < GXN; ++i) {
    float xs = g.x1 + (g.x2 - g.x1) * ((GX0 + i) * (1.f / 7.f));
    xs = fminf(fmaxf(xs, 0.f), 63.f);
    float xf = floorf(xs);
    ix0[i] = (int)xf; ix1[i] = min(ix0[i] + 1, 63); wx[i] = xs - xf;
  }
  #pragma unroll
  for (int i = 0; i < GYN; ++i) {
    float ys = g.y1 + (g.y2 - g.y1) * ((GY0 + i) * (1.f / 7.f));
    ys = fminf(fmaxf(ys, 0.f), 63.f);
    float yf = floorf(ys);
    iy0[i] = (int)yf; iy1[i] = min(iy0[i] + 1, 63); wy[i] = ys - yf;
  }
  const float* fb = featT + (size_t)g.b * (NH * NW * NC) + c;
  float cg[GYN][GXN];
  #pragma unroll
  for (int gy = 0; gy < GYN; ++gy) {
    int r0 = iy0[gy] * (NW * NC), r1 = iy1[gy] * (NW * NC);
    #pragma unroll
    for (int gx = 0; gx < GXN; ++gx) {
      int c0 = ix0[gx] * NC, c1 = ix1[gx] * NC;
      float v00 = fb[r0 + c0], v01 = fb[r0 + c1];
      float v10 = fb[r1 + c0], v11 = fb[r1 + c1];
      float top = v00 + (v01 - v00) * wx[gx];
      float bot = v10 + (v11 - v10) * wx[gx];
      cg[gy][gx] = top + (bot - top) * wy[gy];
    }
  }
  unsigned short* xp = xbf + (size_t)n * INDIM + c * 49;
  #pragma unroll
  for (int p = P0; p < P0 + PN; ++p)
    #pragma unroll
    for (int q = Q0; q < Q0 + QN; ++q)
      xp[p * 7 + q] = f2bf(0.25f * (cg[p - GY0][q - GX0] + cg[p - GY0][q - GX0 + 1]
                                    + cg[p - GY0 + 1][q - GX0] + cg[p - GY0 + 1][q - GX0 + 1]));
}

__global__ void __launch_bounds__(256) k_roi_base(const float* __restrict__ featT,
                                                  const float* __restrict__ rois,
                                                  unsigned short* __restrict__ xbf) {
  int n = blockIdx.x, qd = blockIdx.y, c = threadIdx.x;
  switch (qd) {
    case 0: roi_base_quad<0, 4, 0, 3, 0, 4, 0, 3>(featT, rois, xbf, n, c); break;
    case 1: roi_base_quad<0, 4, 0, 3, 3, 5, 3, 4>(featT, rois, xbf, n, c); break;
    case 2: roi_base_quad<3, 5, 3, 4, 0, 4, 0, 3>(featT, rois, xbf, n, c); break;
    default: roi_base_quad<3, 5, 3, 4, 3, 5, 3, 4>(featT, rois, xbf, n, c); break;
  }
}

// ---------------------------------------------------------------------------
// 4) GEMM1: h_partial = x @ W1^T, split-K. M=256 full (W1 read once from HBM).
__global__ void __launch_bounds__(256) k_gemm1(const unsigned short* __restrict__ A,
                                               const float* __restrict__ W1,
                                               float* __restrict__ partial) {
  __shared__ unsigned short As[256 * 40];   // 256 x 32, pad to 40 (bank spread)
  __shared__ unsigned short Bs[64 * 40];
  int nb = blockIdx.x, kc = blockIdx.y;
  int j0 = nb * 64;
  int kbase = kc * KCLEN;
  int tid = threadIdx.x;
  int wv = tid >> 6, lane = tid & 63;
  int quad = lane >> 4, l15 = lane & 15;
  int m0 = wv * 64;
  floatx4 acc[4][4];
  #pragma unroll
  for (int i = 0; i < 4; ++i)
    #pragma unroll
    for (int j = 0; j < 4; ++j) acc[i][j] = (floatx4)0.0f;

  for (int ks = 0; ks < KCLEN / 32; ++ks) {  // 49 steps
    int kk = kbase + ks * 32;
    #pragma unroll
    for (int rr = 0; rr < 4; ++rr) {
      int q = tid + rr * 256;
      int row = q >> 2, part = q & 3;
      short8 av = *(const short8*)(A + (size_t)row * INDIM + kk + part * 8);
      *(short8*)(As + row * 40 + part * 8) = av;
    }
    #pragma unroll
    for (int rr = 0; rr < 2; ++rr) {
      int q = tid + rr * 256;
      int row = q >> 3, part = q & 7;
      floatx4 bv = *(const floatx4*)(W1 + (size_t)(j0 + row) * INDIM + kk + part * 4);
      union { unsigned short us[4]; unsigned long long u; } cv;
      cv.us[0] = f2bf(bv.x); cv.us[1] = f2bf(bv.y);
      cv.us[2] = f2bf(bv.z); cv.us[3] = f2bf(bv.w);
      *(unsigned long long*)(Bs + row * 40 + part * 4) = cv.u;
    }
    __syncthreads();
    short8 af[4];
    #pragma unroll
    for (int mi = 0; mi < 4; ++mi)   // A frag: A[m=lane&15][k=quad*8+i]
      af[mi] = *(const short8*)(As + (m0 + mi * 16 + l15) * 40 + quad * 8);
    #pragma unroll
    for (int ni = 0; ni < 4; ++ni) { // B frag: B[k=quad*8+i][n=lane&15]
      short8 bfv = *(const short8*)(Bs + (ni * 16 + l15) * 40 + quad * 8);
      #pragma unroll
      for (int mi = 0; mi < 4; ++mi)
        acc[mi][ni] = __builtin_amdgcn_mfma_f32_16x16x32_bf16(af[mi], bfv, acc[mi][ni], 0, 0, 0);
    }
    __syncthreads();
  }
  float* po = partial + (size_t)kc * (NROI * HID);
  #pragma unroll
  for (int mi = 0; mi < 4; ++mi) {
    #pragma unroll
    for (int ni = 0; ni < 4; ++ni) {
      int j = j0 + ni * 16 + l15;
      #pragma unroll
      for (int rg = 0; rg < 4; ++rg) {
        int m = m0 + mi * 16 + quad * 4 + rg;
        po[(size_t)m * HID + j] = acc[mi][ni][rg];
      }
    }
  }
}

// ---------------------------------------------------------------------------
// 5) reduce split-K partials + bias + BN + ReLU -> h bf16 [NROI, HID]
__global__ void k_reduce(const float* __restrict__ partial, const float* __restrict__ b1,
                         const float* __restrict__ g1, const float* __restrict__ be1,
                         const float* __restrict__ m1, const float* __restrict__ v1,
                         unsigned short* __restrict__ h) {
  int idx = blockIdx.x * 256 + threadIdx.x;   // NROI*HID = 1048576
  int j = idx & (HID - 1);
  float s = 0.f;
  #pragma unroll
  for (int kc = 0; kc < KCH; ++kc) s += partial[kc * (NROI * HID) + idx];
  s += b1[j];
  s = (s - m1[j]) * rsqrtf(v1[j] + 1e-5f) * g1[j] + be1[j];
  s = fmaxf(s, 0.f);
  h[idx] = f2bf(s);
}

// ---------------------------------------------------------------------------
// 6) head: o = h @ W2^T + b2, BN, softmax over 12 -> wgt [NROI, 12] fp32
__global__ void k_head(const unsigned short* __restrict__ h, const float* __restrict__ W2,
                       const float* __restrict__ b2, const float* __restrict__ g2,
                       const float* __restrict__ be2, const float* __restrict__ m2,
                       const float* __restrict__ v2, float* __restrict__ wgt) {
  int n = blockIdx.x;
  int tid = threadIdx.x;
  float p[NKF];
  #pragma unroll
  for (int j = 0; j < NKF; ++j) p[j] = 0.f;
  for (int k = tid; k < HID; k += 256) {
    float hv = bf2f(h[n * HID + k]);
    #pragma unroll
    for (int j = 0; j < NKF; ++j) p[j] += hv * W2[j * HID + k];
  }
  #pragma unroll
  for (int j = 0; j < NKF; ++j) {
    #pragma unroll
    for (int off = 32; off > 0; off >>= 1) p[j] += __shfl_down(p[j], off, 64);
  }
  __shared__ float red[4][NKF];
  int wv = tid >> 6, lane = tid & 63;
  if (lane == 0) {
    #pragma unroll
    for (int j = 0; j < NKF; ++j) red[wv][j] = p[j];
  }
  __syncthreads();
  if (tid == 0) {
    float o[NKF], mx = -1e30f;
    #pragma unroll
    for (int j = 0; j < NKF; ++j) {
      float t = red[0][j] + red[1][j] + red[2][j] + red[3][j] + b2[j];
      t = (t - m2[j]) * rsqrtf(v2[j] + 1e-5f) * g2[j] + be2[j];
      o[j] = t;
      mx = fmaxf(mx, t);
    }
    float s = 0.f;
    #pragma unroll
    for (int j = 0; j < NKF; ++j) { o[j] = __expf(o[j] - mx); s += o[j]; }
    float inv = 1.f / s;
    #pragma unroll
    for (int j = 0; j < NKF; ++j) wgt[n * NKF + j] = o[j] * inv;
  }
}

// ---------------------------------------------------------------------------
// 7) final: out[n,c,p,q] = sum_k wgt[n,k] * RoIAlignAvg(filtered_k)[n,c,p,q]
//    quadrant-split; filteredT k-innermost so 3 short4 loads grab all 12 k.
template<int GY0, int GYN, int P0, int PN, int GX0, int GXN, int Q0, int QN>
__device__ __forceinline__ void final_quad(const unsigned short* __restrict__ fT,
                                           const float* __restrict__ rois,
                                           const float* __restrict__ wgt,
                                           float* __restrict__ out, int n, int c) {
  RoiGeom g = roi_geom(rois, n);
  int ix0[GXN], ix1[GXN], iy0[GYN], iy1[GYN];
  float wx[GXN], wy[GYN];
  #pragma unroll
  for (int i = 0; i < GXN; ++i) {
    float xs = g.x1 + (g.x2 - g.x1) * ((GX0 + i) * (1.f / 7.f));
    xs = fminf(fmaxf(xs, 0.f), 63.f);
    float xf = floorf(xs);
    ix0[i] = (int)xf; ix1[i] = min(ix0[i] + 1, 63); wx[i] = xs - xf;
  }
  #pragma unroll
  for (int i = 0; i < GYN; ++i) {
    float ys = g.y1 + (g.y2 - g.y1) * ((GY0 + i) * (1.f / 7.f));
    ys = fminf(fmaxf(ys, 0.f), 63.f);
    float yf = floorf(ys);
    iy0[i] = (int)yf; iy1[i] = min(iy0[i] + 1, 63); wy[i] = ys - yf;
  }
  float wk[NKF];
  #pragma unroll
  for (int k = 0; k < NKF; ++k) wk[k] = wgt[n * NKF + k];

  const unsigned short* fb = fT + (size_t)g.b * (NH * NW * NC * NKF) + c * NKF;
  float cg[GYN][GXN];
  #pragma unroll
  for (int gy = 0; gy < GYN; ++gy) {
    size_t r0 = (size_t)iy0[gy] * (NW * NC * NKF), r1 = (size_t)iy1[gy] * (NW * NC * NKF);
    #pragma unroll
    for (int gx = 0; gx < GXN; ++gx) {
      size_t c0 = (size_t)ix0[gx] * (NC * NKF), c1 = (size_t)ix1[gx] * (NC * NKF);
      const unsigned short* p00 = fb + r0 + c0;
      const unsigned short* p01 = fb + r0 + c1;
      const unsigned short* p10 = fb + r1 + c0;
      const unsigned short* p11 = fb + r1 + c1;
      short4v a00[3], a01[3], a10[3], a11[3];
      #pragma unroll
      for (int m = 0; m < 3; ++m) {
        a00[m] = *(const short4v*)(p00 + m * 4);
        a01[m] = *(const short4v*)(p01 + m * 4);
        a10[m] = *(const short4v*)(p10 + m * 4);
        a11[m] = *(const short4v*)(p11 + m * 4);
      }
      float accv = 0.f;
      #pragma unroll
      for (int m = 0; m < 3; ++m) {
        #pragma unroll
        for (int j = 0; j < 4; ++j) {
          float v00 = bf2f((unsigned short)a00[m][j]);
          float v01 = bf2f((unsigned short)a01[m][j]);
          float v10 = bf2f((unsigned short)a10[m][j]);
          float v11 = bf2f((unsigned short)a11[m][j]);
          float top = v00 + (v01 - v00) * wx[gx];
          float bot = v10 + (v11 - v10) * wx[gx];
          accv += wk[m * 4 + j] * (top + (bot - top) * wy[gy]);
        }
      }
      cg[gy][gx] = accv;
    }
  }
  float* op = out + ((size_t)n * NC + c) * 49;
  #pragma unroll
  for (int p = P0; p < P0 + PN; ++p)
    #pragma unroll
    for (int q = Q0; q < Q0 + QN; ++q)
      op[p * 7 + q] = 0.25f * (cg[p - GY0][q - GX0] + cg[p - GY0][q - GX0 + 1]
                               + cg[p - GY0 + 1][q - GX0] + cg[p - GY0 + 1][q - GX0 + 1]);
}

__global__ void __launch_bounds__(256, 4) k_final(const unsigned short* __restrict__ fT,
                                                  const float* __restrict__ rois,
                                                  const float* __restrict__ wgt,
                                                  float* __restrict__ out) {
  int n = blockIdx.x, qd = blockIdx.y, c = threadIdx.x;
  switch (qd) {
    case 0: final_quad<0, 4, 0, 3, 0, 4, 0, 3>(fT, rois, wgt, out, n, c); break;
    case 1: final_quad<0, 4, 0, 3, 3, 5, 3, 4>(fT, rois, wgt, out, n, c); break;
    case 2: final_quad<3, 5, 3, 4, 0, 4, 0, 3>(fT, rois, wgt, out, n, c); break;
    default: final_quad<3, 5, 3, 4, 3, 5, 3, 4>(fT, rois, wgt, out, n, c); break;
  }
}

// ---------------------------------------------------------------------------
extern "C" void kernel_launch(void* const* d_in, const int* in_sizes, int n_in,
                              void* d_out, int out_size, void* d_ws, size_t ws_size,
                              hipStream_t stream) {
  const float* base = (const float*)d_in[0];
  const float* kern = (const float*)d_in[1];
  const float* rois = (const float*)d_in[2];
  const float* W1  = (const float*)d_in[3];
  const float* b1  = (const float*)d_in[4];
  const float* g1  = (const float*)d_in[5];
  const float* be1 = (const float*)d_in[6];
  const float* m1  = (const float*)d_in[7];
  const float* v1  = (const float*)d_in[8];
  const float* W2  = (const float*)d_in[9];
  const float* b2  = (const float*)d_in[10];
  const float* g2  = (const float*)d_in[11];
  const float* be2 = (const float*)d_in[12];
  const float* m2  = (const float*)d_in[13];
  const float* v2  = (const float*)d_in[14];
  float* out = (float*)d_out;

  // workspace layout (≈100.8 MiB total)
  char* ws = (char*)d_ws;
  float*          featT     = (float*)(ws);                    //  8 MiB  [B,H,W,C] fp32
  unsigned short* filteredT = (unsigned short*)(ws + 8388608); // 48 MiB  [B,H,W,C,12] bf16
  unsigned short* xbf       = (unsigned short*)(ws + 58720256);//  6.1 MiB [NROI, 12544] bf16
  float*          partial   = (float*)(ws + 65142784);         // 32 MiB  [8, NROI, HID] fp32
  unsigned short* hbf       = (unsigned short*)(ws + 98697216);//  2 MiB  [NROI, HID] bf16
  float*          wgt       = (float*)(ws + 100794368);        // 12 KiB  [NROI, 12] fp32

  hipLaunchKernelGGL(k_transpose, dim3(NB * NH), dim3(256), 0, stream, base, featT);
  hipLaunchKernelGGL(k_conv, dim3(NB * NH * 4), dim3(256), 0, stream, featT, kern, filteredT);
  hipLaunchKernelGGL(k_roi_base, dim3(NROI, 4), dim3(256), 0, stream, featT, rois, xbf);
  hipLaunchKernelGGL(k_gemm1, dim3(64, KCH), dim3(256), 0, stream, xbf, W1, partial);
  hipLaunchKernelGGL(k_reduce, dim3(NROI * HID / 256), dim3(256), 0, stream,
                     partial, b1, g1, be1, m1, v1, hbf);
  hipLaunchKernelGGL(k_head, dim3(NROI), dim3(256), 0, stream, hbf, W2, b2, g2, be2, m2, v2, wgt);
  hipLaunchKernelGGL(k_final, dim3(NROI, 4), dim3(256), 0, stream, filteredT, rois, wgt, out);
}

// Round 3
// 799.543 us; speedup vs baseline: 1.4751x; 1.1239x over previous
//
#include <hip/hip_runtime.h>

// Problem constants (fixed by reference)
#define NB    2          // batch
#define NC    256        // channels
#define NH    64
#define NW    64
#define PADW  72         // zero-padded spatial dim (3 halo + room for 8x8 smear window)
#define NKF   12         // num gaussian kernels
#define NROI  256        // B*R
#define HID   4096
#define INDIM 12544      // 256*49
#define KCH   8          // split-K chunks for GEMM1
#define KCLEN 1568       // 12544/8

typedef __attribute__((ext_vector_type(8))) short short8;
typedef __attribute__((ext_vector_type(4))) float floatx4;

__device__ __forceinline__ unsigned short f2bf(float f) {
  unsigned int u = __float_as_uint(f);
  u += 0x7fffu + ((u >> 16) & 1u);   // round-to-nearest-even
  return (unsigned short)(u >> 16);
}

// ---------------------------------------------------------------------------
// 1) base_feat [B,C,H,W] -> featT [B,72,72,C] fp32, zero-padded 3-halo.
//    Pad implements conv's zero padding for free (memset-ed before launch).
__global__ void k_transpose(const float* __restrict__ base, float* __restrict__ featT) {
  int bid = blockIdx.x;            // B*H = 128
  int b = bid >> 6, y = bid & 63;
  __shared__ float tile[64][65];
  for (int cc = 0; cc < 4; ++cc) {
    int c0 = cc * 64;
    #pragma unroll
    for (int i = 0; i < 16; ++i) {
      int idx = threadIdx.x + i * 256;
      int ci = idx >> 6, xi = idx & 63;
      tile[ci][xi] = base[(((b * NC) + c0 + ci) * NH + y) * NW + xi];
    }
    __syncthreads();
    #pragma unroll
    for (int i = 0; i < 16; ++i) {
      int idx = threadIdx.x + i * 256;
      int xo = idx >> 6, co = idx & 63;
      featT[(((size_t)b * PADW + y + 3) * PADW + xo + 3) * NC + c0 + co] = tile[co][xo];
    }
    __syncthreads();
  }
}

// ---------------------------------------------------------------------------
// shared roi geometry helper
struct RoiGeom {
  int b;
  float x1, y1, x2, y2;
};
__device__ __forceinline__ RoiGeom roi_geom(const float* __restrict__ rois, int n) {
  const float* r = rois + n * 5;
  RoiGeom g;
  g.b = (int)r[0];
  g.x1 = r[1] * 0.0625f; g.y1 = r[2] * 0.0625f;
  g.x2 = r[3] * 0.0625f; g.y2 = r[4] * 0.0625f;
  return g;
}

// ---------------------------------------------------------------------------
// 2) RoIAlignAvg of base -> MLP input x [NROI, 12544] bf16 (c-major, 7x7 minor)
template<int GY0, int GYN, int P0, int PN, int GX0, int GXN, int Q0, int QN>
__device__ __forceinline__ void roi_base_quad(const float* __restrict__ featT,
                                              const float* __restrict__ rois,
                                              unsigned short* __restrict__ xbf,
                                              int n, int c) {
  RoiGeom g = roi_geom(rois, n);
  int ix0[GXN], ix1[GXN], iy0[GYN], iy1[GYN];
  float wx[GXN], wy[GYN];
  #pragma unroll
  for (int i = 0; i < GXN; ++i) {
    float xs = g.x1 + (g.x2 - g.x1) * ((GX0 + i) * (1.f / 7.f));
    xs = fminf(fmaxf(xs, 0.f), 63.f);
    float xf = floorf(xs);
    ix0[i] = (int)xf; ix1[i] = min(ix0[i] + 1, 63); wx[i] = xs - xf;
  }
  #pragma unroll
  for (int i = 0; i < GYN; ++i) {
    float ys = g.y1 + (g.y2 - g.y1) * ((GY0 + i) * (1.f / 7.f));
    ys = fminf(fmaxf(ys, 0.f), 63.f);
    float yf = floorf(ys);
    iy0[i] = (int)yf; iy1[i] = min(iy0[i] + 1, 63); wy[i] = ys - yf;
  }
  const float* fb = featT + ((size_t)g.b * (PADW * PADW) + 3 * PADW + 3) * NC + c;
  float cg[GYN][GXN];
  #pragma unroll
  for (int gy = 0; gy < GYN; ++gy) {
    int r0 = iy0[gy] * (PADW * NC), r1 = iy1[gy] * (PADW * NC);
    #pragma unroll
    for (int gx = 0; gx < GXN; ++gx) {
      int c0 = ix0[gx] * NC, c1 = ix1[gx] * NC;
      float v00 = fb[r0 + c0], v01 = fb[r0 + c1];
      float v10 = fb[r1 + c0], v11 = fb[r1 + c1];
      float top = v00 + (v01 - v00) * wx[gx];
      float bot = v10 + (v11 - v10) * wx[gx];
      cg[gy][gx] = top + (bot - top) * wy[gy];
    }
  }
  unsigned short* xp = xbf + (size_t)n * INDIM + c * 49;
  #pragma unroll
  for (int p = P0; p < P0 + PN; ++p)
    #pragma unroll
    for (int q = Q0; q < Q0 + QN; ++q)
      xp[p * 7 + q] = f2bf(0.25f * (cg[p - GY0][q - GX0] + cg[p - GY0][q - GX0 + 1]
                                    + cg[p - GY0 + 1][q - GX0] + cg[p - GY0 + 1][q - GX0 + 1]));
}

__global__ void __launch_bounds__(256) k_roi_base(const float* __restrict__ featT,
                                                  const float* __restrict__ rois,
                                                  unsigned short* __restrict__ xbf) {
  int n = blockIdx.x, qd = blockIdx.y, c = threadIdx.x;
  switch (qd) {
    case 0: roi_base_quad<0, 4, 0, 3, 0, 4, 0, 3>(featT, rois, xbf, n, c); break;
    case 1: roi_base_quad<0, 4, 0, 3, 3, 5, 3, 4>(featT, rois, xbf, n, c); break;
    case 2: roi_base_quad<3, 5, 3, 4, 0, 4, 0, 3>(featT, rois, xbf, n, c); break;
    default: roi_base_quad<3, 5, 3, 4, 3, 5, 3, 4>(featT, rois, xbf, n, c); break;
  }
}

// ---------------------------------------------------------------------------
// 3) GEMM1: partial = x @ W1^T, split-K. M=256 full (W1 read once from HBM).
__global__ void __launch_bounds__(256) k_gemm1(const unsigned short* __restrict__ A,
                                               const float* __restrict__ W1,
                                               float* __restrict__ partial) {
  __shared__ unsigned short As[256 * 40];
  __shared__ unsigned short Bs[64 * 40];
  int nb = blockIdx.x, kc = blockIdx.y;
  int j0 = nb * 64;
  int kbase = kc * KCLEN;
  int tid = threadIdx.x;
  int wv = tid >> 6, lane = tid & 63;
  int quad = lane >> 4, l15 = lane & 15;
  int m0 = wv * 64;
  floatx4 acc[4][4];
  #pragma unroll
  for (int i = 0; i < 4; ++i)
    #pragma unroll
    for (int j = 0; j < 4; ++j) acc[i][j] = (floatx4)0.0f;

  for (int ks = 0; ks < KCLEN / 32; ++ks) {  // 49 steps
    int kk = kbase + ks * 32;
    #pragma unroll
    for (int rr = 0; rr < 4; ++rr) {
      int q = tid + rr * 256;
      int row = q >> 2, part = q & 3;
      short8 av = *(const short8*)(A + (size_t)row * INDIM + kk + part * 8);
      *(short8*)(As + row * 40 + part * 8) = av;
    }
    #pragma unroll
    for (int rr = 0; rr < 2; ++rr) {
      int q = tid + rr * 256;
      int row = q >> 3, part = q & 7;
      floatx4 bv = *(const floatx4*)(W1 + (size_t)(j0 + row) * INDIM + kk + part * 4);
      union { unsigned short us[4]; unsigned long long u; } cv;
      cv.us[0] = f2bf(bv.x); cv.us[1] = f2bf(bv.y);
      cv.us[2] = f2bf(bv.z); cv.us[3] = f2bf(bv.w);
      *(unsigned long long*)(Bs + row * 40 + part * 4) = cv.u;
    }
    __syncthreads();
    short8 af[4];
    #pragma unroll
    for (int mi = 0; mi < 4; ++mi)
      af[mi] = *(const short8*)(As + (m0 + mi * 16 + l15) * 40 + quad * 8);
    #pragma unroll
    for (int ni = 0; ni < 4; ++ni) {
      short8 bfv = *(const short8*)(Bs + (ni * 16 + l15) * 40 + quad * 8);
      #pragma unroll
      for (int mi = 0; mi < 4; ++mi)
        acc[mi][ni] = __builtin_amdgcn_mfma_f32_16x16x32_bf16(af[mi], bfv, acc[mi][ni], 0, 0, 0);
    }
    __syncthreads();
  }
  float* po = partial + (size_t)kc * (NROI * HID);
  #pragma unroll
  for (int mi = 0; mi < 4; ++mi) {
    #pragma unroll
    for (int ni = 0; ni < 4; ++ni) {
      int j = j0 + ni * 16 + l15;
      #pragma unroll
      for (int rg = 0; rg < 4; ++rg) {
        int m = m0 + mi * 16 + quad * 4 + rg;
        po[(size_t)m * HID + j] = acc[mi][ni][rg];
      }
    }
  }
}

// ---------------------------------------------------------------------------
// 4) fused: reduce split-K + bias + BN + ReLU + head GEMV + BN + softmax -> wgt
__global__ void __launch_bounds__(256) k_reduce_head(
    const float* __restrict__ partial,
    const float* __restrict__ b1, const float* __restrict__ g1,
    const float* __restrict__ be1, const float* __restrict__ m1,
    const float* __restrict__ v1, const float* __restrict__ W2,
    const float* __restrict__ b2, const float* __restrict__ g2,
    const float* __restrict__ be2, const float* __restrict__ m2,
    const float* __restrict__ v2, float* __restrict__ wgt) {
  int n = blockIdx.x, tid = threadIdx.x;
  float p[NKF];
  #pragma unroll
  for (int k = 0; k < NKF; ++k) p[k] = 0.f;
  #pragma unroll 4
  for (int jj = 0; jj < HID / 256; ++jj) {
    int j = jj * 256 + tid;
    float s = 0.f;
    #pragma unroll
    for (int kc = 0; kc < KCH; ++kc)
      s += partial[(size_t)kc * (NROI * HID) + (size_t)n * HID + j];
    s += b1[j];
    s = (s - m1[j]) * rsqrtf(v1[j] + 1e-5f) * g1[j] + be1[j];
    s = fmaxf(s, 0.f);
    #pragma unroll
    for (int k = 0; k < NKF; ++k) p[k] += s * W2[k * HID + j];
  }
  #pragma unroll
  for (int k = 0; k < NKF; ++k) {
    #pragma unroll
    for (int off = 32; off > 0; off >>= 1) p[k] += __shfl_down(p[k], off, 64);
  }
  __shared__ float red[4][NKF];
  int wv = tid >> 6, lane = tid & 63;
  if (lane == 0) {
    #pragma unroll
    for (int k = 0; k < NKF; ++k) red[wv][k] = p[k];
  }
  __syncthreads();
  if (tid == 0) {
    float o[NKF], mx = -1e30f;
    #pragma unroll
    for (int k = 0; k < NKF; ++k) {
      float t = red[0][k] + red[1][k] + red[2][k] + red[3][k] + b2[k];
      t = (t - m2[k]) * rsqrtf(v2[k] + 1e-5f) * g2[k] + be2[k];
      o[k] = t;
      mx = fmaxf(mx, t);
    }
    float s = 0.f;
    #pragma unroll
    for (int k = 0; k < NKF; ++k) { o[k] = __expf(o[k] - mx); s += o[k]; }
    float inv = 1.f / s;
    #pragma unroll
    for (int k = 0; k < NKF; ++k) wgt[n * NKF + k] = o[k] * inv;
  }
}

// ---------------------------------------------------------------------------
// 5) final (merged kernel): out[n] = RoIAlign(conv(base, sum_k wgt[n,k] K_k)).
//    Per sample: conv+bilinear collapse to one 8x8 smeared stencil (bmk) over
//    the zero-padded fp32 base. No filtered maps, no bf16, fully linear-exact.
template<int GY0, int GYN, int P0, int PN, int GX0, int GXN, int Q0, int QN>
__device__ __forceinline__ void final_quad_m(
    const float* __restrict__ featT, const float* __restrict__ rois,
    const float* __restrict__ wgt, const float* __restrict__ kern,
    float* __restrict__ out, int n,
    float* mk, float* bmk, int* sx0i, int* sy0i, float* swx, float* swy) {
  const int S = GYN * GXN;
  int tid = threadIdx.x;
  const float* r = rois + n * 5;
  int b = (int)r[0];
  // phase A: merged 7x7 kernel (threads 0..48) + per-sample geometry (64..64+S)
  if (tid < 49) {
    float m = 0.f;
    #pragma unroll
    for (int k = 0; k < NKF; ++k)
      m += wgt[n * NKF + k] * kern[k * (NC * 49) + tid];   // channel-identical
    mk[tid] = m;
  } else if (tid >= 64 && tid < 64 + S) {
    int s = tid - 64;
    int gy = GY0 + s / GXN, gx = GX0 + s % GXN;
    float x1 = r[1] * 0.0625f, y1 = r[2] * 0.0625f;
    float x2 = r[3] * 0.0625f, y2 = r[4] * 0.0625f;
    float xs = fminf(fmaxf(x1 + (x2 - x1) * (gx * (1.f / 7.f)), 0.f), 63.f);
    float ys = fminf(fmaxf(y1 + (y2 - y1) * (gy * (1.f / 7.f)), 0.f), 63.f);
    float xf = floorf(xs), yf = floorf(ys);
    sx0i[s] = (int)xf; sy0i[s] = (int)yf;
    swx[s] = xs - xf;  swy[s] = ys - yf;
  }
  __syncthreads();
  // phase B: smear mk (7x7) with 2x2 bilinear weights -> bmk[s][8x8]
  for (int u = tid; u < S * 64; u += 256) {
    int s = u >> 6, e = u & 63, i = e >> 3, j = e & 7;
    float wx = swx[s], wy = swy[s];
    float w00 = (1.f - wy) * (1.f - wx), w01 = (1.f - wy) * wx;
    float w10 = wy * (1.f - wx),         w11 = wy * wx;
    float v = 0.f;
    if (i < 7 && j < 7)   v += w00 * mk[i * 7 + j];
    if (i < 7 && j >= 1)  v += w01 * mk[i * 7 + j - 1];
    if (i >= 1 && j < 7)  v += w10 * mk[(i - 1) * 7 + j];
    if (i >= 1 && j >= 1) v += w11 * mk[(i - 1) * 7 + j - 1];
    bmk[u] = v;
  }
  __syncthreads();
  // phase C: evaluate samples (64 coalesced loads + 64 FMA each), pool, store
  int c = tid;
  const float* fb = featT + (size_t)b * (PADW * PADW * NC) + c;
  float cg[GYN][GXN];
  #pragma unroll
  for (int a = 0; a < GYN; ++a) {
    #pragma unroll
    for (int q = 0; q < GXN; ++q) {
      int s = a * GXN + q;
      int y0 = sy0i[s], x0 = sx0i[s];
      // padded coord of window origin (y0-3, x0-3) is exactly (y0, x0)
      const float* p = fb + ((size_t)y0 * PADW + x0) * NC;
      const floatx4* wv = (const floatx4*)(bmk + s * 64);
      float acc = 0.f;
      #pragma unroll
      for (int i = 0; i < 8; ++i) {
        floatx4 w0 = wv[i * 2], w1 = wv[i * 2 + 1];
        const float* pi = p + (size_t)i * (PADW * NC);
        acc += w0.x * pi[0]      + w0.y * pi[NC]     + w0.z * pi[2 * NC] + w0.w * pi[3 * NC];
        acc += w1.x * pi[4 * NC] + w1.y * pi[5 * NC] + w1.z * pi[6 * NC] + w1.w * pi[7 * NC];
      }
      cg[a][q] = acc;
    }
  }
  float* op = out + ((size_t)n * NC + c) * 49;
  #pragma unroll
  for (int p = P0; p < P0 + PN; ++p)
    #pragma unroll
    for (int q = Q0; q < Q0 + QN; ++q)
      op[p * 7 + q] = 0.25f * (cg[p - GY0][q - GX0] + cg[p - GY0][q - GX0 + 1]
                               + cg[p - GY0 + 1][q - GX0] + cg[p - GY0 + 1][q - GX0 + 1]);
}

__global__ void __launch_bounds__(256, 4) k_final(const float* __restrict__ featT,
                                                  const float* __restrict__ rois,
                                                  const float* __restrict__ wgt,
                                                  const float* __restrict__ kern,
                                                  float* __restrict__ out) {
  __shared__ float mk[49];
  __shared__ __align__(16) float bmk[25 * 64];
  __shared__ int sx0i[25];
  __shared__ int sy0i[25];
  __shared__ float swx[25];
  __shared__ float swy[25];
  int n = blockIdx.x, qd = blockIdx.y;
  switch (qd) {
    case 0: final_quad_m<0, 4, 0, 3, 0, 4, 0, 3>(featT, rois, wgt, kern, out, n, mk, bmk, sx0i, sy0i, swx, swy); break;
    case 1: final_quad_m<0, 4, 0, 3, 3, 5, 3, 4>(featT, rois, wgt, kern, out, n, mk, bmk, sx0i, sy0i, swx, swy); break;
    case 2: final_quad_m<3, 5, 3, 4, 0, 4, 0, 3>(featT, rois, wgt, kern, out, n, mk, bmk, sx0i, sy0i, swx, swy); break;
    default: final_quad_m<3, 5, 3, 4, 3, 5, 3, 4>(featT, rois, wgt, kern, out, n, mk, bmk, sx0i, sy0i, swx, swy); break;
  }
}

// ---------------------------------------------------------------------------
extern "C" void kernel_launch(void* const* d_in, const int* in_sizes, int n_in,
                              void* d_out, int out_size, void* d_ws, size_t ws_size,
                              hipStream_t stream) {
  const float* base = (const float*)d_in[0];
  const float* kern = (const float*)d_in[1];
  const float* rois = (const float*)d_in[2];
  const float* W1  = (const float*)d_in[3];
  const float* b1  = (const float*)d_in[4];
  const float* g1  = (const float*)d_in[5];
  const float* be1 = (const float*)d_in[6];
  const float* m1  = (const float*)d_in[7];
  const float* v1  = (const float*)d_in[8];
  const float* W2  = (const float*)d_in[9];
  const float* b2  = (const float*)d_in[10];
  const float* g2  = (const float*)d_in[11];
  const float* be2 = (const float*)d_in[12];
  const float* m2  = (const float*)d_in[13];
  const float* v2  = (const float*)d_in[14];
  float* out = (float*)d_out;

  // workspace layout (~50.6 MiB total)
  char* ws = (char*)d_ws;
  const size_t FEATT_BYTES = (size_t)NB * PADW * PADW * NC * 4;   // 10,616,832
  float*          featT   = (float*)(ws);
  unsigned short* xbf     = (unsigned short*)(ws + 10616832);     // 6,422,528
  float*          partial = (float*)(ws + 17039360);              // 33,554,432
  float*          wgt     = (float*)(ws + 50593792);              // 12,288

  hipMemsetAsync(featT, 0, FEATT_BYTES, stream);   // zero halo for conv padding
  hipLaunchKernelGGL(k_transpose, dim3(NB * NH), dim3(256), 0, stream, base, featT);
  hipLaunchKernelGGL(k_roi_base, dim3(NROI, 4), dim3(256), 0, stream, featT, rois, xbf);
  hipLaunchKernelGGL(k_gemm1, dim3(64, KCH), dim3(256), 0, stream, xbf, W1, partial);
  hipLaunchKernelGGL(k_reduce_head, dim3(NROI), dim3(256), 0, stream,
                     partial, b1, g1, be1, m1, v1, W2, b2, g2, be2, m2, v2, wgt);
  hipLaunchKernelGGL(k_final, dim3(NROI, 4), dim3(256), 0, stream, featT, rois, wgt, kern, out);
}

// Round 4
// 506.686 us; speedup vs baseline: 2.3276x; 1.5780x over previous
//
#include <hip/hip_runtime.h>

// Problem constants (fixed by reference)
#define NB    2          // batch
#define NC    256        // channels
#define NH    64
#define NW    64
#define PADW  72         // zero-padded spatial dim (3 halo + room for 8x8 smear window)
#define NKF   12         // num gaussian kernels
#define NROI  256        // B*R
#define HID   4096
#define INDIM 12544      // 256*49
#define KCH   8          // split-K chunks for GEMM1
#define KCLEN 1568       // 12544/8

typedef __attribute__((ext_vector_type(8))) short short8;
typedef __attribute__((ext_vector_type(4))) float floatx4;

__device__ __forceinline__ unsigned short f2bf(float f) {
  unsigned int u = __float_as_uint(f);
  u += 0x7fffu + ((u >> 16) & 1u);   // round-to-nearest-even
  return (unsigned short)(u >> 16);
}

// ---------------------------------------------------------------------------
// 1) base_feat [B,C,H,W] -> featT [B,72,72,C] fp32 (padded) + featB bf16 copy.
__global__ void k_transpose(const float* __restrict__ base, float* __restrict__ featT,
                            unsigned short* __restrict__ featB) {
  int bid = blockIdx.x;            // B*H = 128
  int b = bid >> 6, y = bid & 63;
  __shared__ float tile[64][65];
  for (int cc = 0; cc < 4; ++cc) {
    int c0 = cc * 64;
    #pragma unroll
    for (int i = 0; i < 16; ++i) {
      int idx = threadIdx.x + i * 256;
      int ci = idx >> 6, xi = idx & 63;
      tile[ci][xi] = base[(((b * NC) + c0 + ci) * NH + y) * NW + xi];
    }
    __syncthreads();
    #pragma unroll
    for (int i = 0; i < 16; ++i) {
      int idx = threadIdx.x + i * 256;
      int xo = idx >> 6, co = idx & 63;
      float v = tile[co][xo];
      size_t o = (((size_t)b * PADW + y + 3) * PADW + xo + 3) * NC + c0 + co;
      featT[o] = v;
      featB[o] = f2bf(v);
    }
    __syncthreads();
  }
}

// ---------------------------------------------------------------------------
// 2) RoIAlignAvg of base -> MLP input x [NROI, 12544] bf16 (c-major, 7x7 minor)
template<int GY0, int GYN, int P0, int PN, int GX0, int GXN, int Q0, int QN>
__device__ __forceinline__ void roi_base_quad(const float* __restrict__ featT,
                                              const float* __restrict__ rois,
                                              unsigned short* __restrict__ xbf,
                                              int n, int c) {
  const float* r = rois + n * 5;
  int b = (int)r[0];
  float x1 = r[1] * 0.0625f, y1 = r[2] * 0.0625f;
  float x2 = r[3] * 0.0625f, y2 = r[4] * 0.0625f;
  int ix0[GXN], ix1[GXN], iy0[GYN], iy1[GYN];
  float wx[GXN], wy[GYN];
  #pragma unroll
  for (int i = 0; i < GXN; ++i) {
    float xs = fminf(fmaxf(x1 + (x2 - x1) * ((GX0 + i) * (1.f / 7.f)), 0.f), 63.f);
    float xf = floorf(xs);
    ix0[i] = (int)xf; ix1[i] = min(ix0[i] + 1, 63); wx[i] = xs - xf;
  }
  #pragma unroll
  for (int i = 0; i < GYN; ++i) {
    float ys = fminf(fmaxf(y1 + (y2 - y1) * ((GY0 + i) * (1.f / 7.f)), 0.f), 63.f);
    float yf = floorf(ys);
    iy0[i] = (int)yf; iy1[i] = min(iy0[i] + 1, 63); wy[i] = ys - yf;
  }
  const float* fb = featT + ((size_t)b * (PADW * PADW) + 3 * PADW + 3) * NC + c;
  float cg[GYN][GXN];
  #pragma unroll
  for (int gy = 0; gy < GYN; ++gy) {
    int r0 = iy0[gy] * (PADW * NC), r1 = iy1[gy] * (PADW * NC);
    #pragma unroll
    for (int gx = 0; gx < GXN; ++gx) {
      int c0 = ix0[gx] * NC, c1 = ix1[gx] * NC;
      float v00 = fb[r0 + c0], v01 = fb[r0 + c1];
      float v10 = fb[r1 + c0], v11 = fb[r1 + c1];
      float top = v00 + (v01 - v00) * wx[gx];
      float bot = v10 + (v11 - v10) * wx[gx];
      cg[gy][gx] = top + (bot - top) * wy[gy];
    }
  }
  unsigned short* xp = xbf + (size_t)n * INDIM + c * 49;
  #pragma unroll
  for (int p = P0; p < P0 + PN; ++p)
    #pragma unroll
    for (int q = Q0; q < Q0 + QN; ++q)
      xp[p * 7 + q] = f2bf(0.25f * (cg[p - GY0][q - GX0] + cg[p - GY0][q - GX0 + 1]
                                    + cg[p - GY0 + 1][q - GX0] + cg[p - GY0 + 1][q - GX0 + 1]));
}

__global__ void __launch_bounds__(256) k_roi_base(const float* __restrict__ featT,
                                                  const float* __restrict__ rois,
                                                  unsigned short* __restrict__ xbf) {
  int n = blockIdx.x, qd = blockIdx.y, c = threadIdx.x;
  switch (qd) {
    case 0: roi_base_quad<0, 4, 0, 3, 0, 4, 0, 3>(featT, rois, xbf, n, c); break;
    case 1: roi_base_quad<0, 4, 0, 3, 3, 5, 3, 4>(featT, rois, xbf, n, c); break;
    case 2: roi_base_quad<3, 5, 3, 4, 0, 4, 0, 3>(featT, rois, xbf, n, c); break;
    default: roi_base_quad<3, 5, 3, 4, 3, 5, 3, 4>(featT, rois, xbf, n, c); break;
  }
}

// ---------------------------------------------------------------------------
// 3) GEMM1: partial = x @ W1^T, split-K. M=256 full (W1 read once from HBM).
__global__ void __launch_bounds__(256) k_gemm1(const unsigned short* __restrict__ A,
                                               const float* __restrict__ W1,
                                               float* __restrict__ partial) {
  __shared__ unsigned short As[256 * 40];
  __shared__ unsigned short Bs[64 * 40];
  int nb = blockIdx.x, kc = blockIdx.y;
  int j0 = nb * 64;
  int kbase = kc * KCLEN;
  int tid = threadIdx.x;
  int wv = tid >> 6, lane = tid & 63;
  int quad = lane >> 4, l15 = lane & 15;
  int m0 = wv * 64;
  floatx4 acc[4][4];
  #pragma unroll
  for (int i = 0; i < 4; ++i)
    #pragma unroll
    for (int j = 0; j < 4; ++j) acc[i][j] = (floatx4)0.0f;

  for (int ks = 0; ks < KCLEN / 32; ++ks) {  // 49 steps
    int kk = kbase + ks * 32;
    #pragma unroll
    for (int rr = 0; rr < 4; ++rr) {
      int q = tid + rr * 256;
      int row = q >> 2, part = q & 3;
      short8 av = *(const short8*)(A + (size_t)row * INDIM + kk + part * 8);
      *(short8*)(As + row * 40 + part * 8) = av;
    }
    #pragma unroll
    for (int rr = 0; rr < 2; ++rr) {
      int q = tid + rr * 256;
      int row = q >> 3, part = q & 7;
      floatx4 bv = *(const floatx4*)(W1 + (size_t)(j0 + row) * INDIM + kk + part * 4);
      union { unsigned short us[4]; unsigned long long u; } cv;
      cv.us[0] = f2bf(bv.x); cv.us[1] = f2bf(bv.y);
      cv.us[2] = f2bf(bv.z); cv.us[3] = f2bf(bv.w);
      *(unsigned long long*)(Bs + row * 40 + part * 4) = cv.u;
    }
    __syncthreads();
    short8 af[4];
    #pragma unroll
    for (int mi = 0; mi < 4; ++mi)
      af[mi] = *(const short8*)(As + (m0 + mi * 16 + l15) * 40 + quad * 8);
    #pragma unroll
    for (int ni = 0; ni < 4; ++ni) {
      short8 bfv = *(const short8*)(Bs + (ni * 16 + l15) * 40 + quad * 8);
      #pragma unroll
      for (int mi = 0; mi < 4; ++mi)
        acc[mi][ni] = __builtin_amdgcn_mfma_f32_16x16x32_bf16(af[mi], bfv, acc[mi][ni], 0, 0, 0);
    }
    __syncthreads();
  }
  float* po = partial + (size_t)kc * (NROI * HID);
  #pragma unroll
  for (int mi = 0; mi < 4; ++mi) {
    #pragma unroll
    for (int ni = 0; ni < 4; ++ni) {
      int j = j0 + ni * 16 + l15;
      #pragma unroll
      for (int rg = 0; rg < 4; ++rg) {
        int m = m0 + mi * 16 + quad * 4 + rg;
        po[(size_t)m * HID + j] = acc[mi][ni][rg];
      }
    }
  }
}

// ---------------------------------------------------------------------------
// 4) fused: reduce split-K + bias + BN + ReLU + head GEMV + BN + softmax -> wgt
__global__ void __launch_bounds__(256) k_reduce_head(
    const float* __restrict__ partial,
    const float* __restrict__ b1, const float* __restrict__ g1,
    const float* __restrict__ be1, const float* __restrict__ m1,
    const float* __restrict__ v1, const float* __restrict__ W2,
    const float* __restrict__ b2, const float* __restrict__ g2,
    const float* __restrict__ be2, const float* __restrict__ m2,
    const float* __restrict__ v2, float* __restrict__ wgt) {
  int n = blockIdx.x, tid = threadIdx.x;
  float p[NKF];
  #pragma unroll
  for (int k = 0; k < NKF; ++k) p[k] = 0.f;
  #pragma unroll 4
  for (int jj = 0; jj < HID / 256; ++jj) {
    int j = jj * 256 + tid;
    float s = 0.f;
    #pragma unroll
    for (int kc = 0; kc < KCH; ++kc)
      s += partial[(size_t)kc * (NROI * HID) + (size_t)n * HID + j];
    s += b1[j];
    s = (s - m1[j]) * rsqrtf(v1[j] + 1e-5f) * g1[j] + be1[j];
    s = fmaxf(s, 0.f);
    #pragma unroll
    for (int k = 0; k < NKF; ++k) p[k] += s * W2[k * HID + j];
  }
  #pragma unroll
  for (int k = 0; k < NKF; ++k) {
    #pragma unroll
    for (int off = 32; off > 0; off >>= 1) p[k] += __shfl_down(p[k], off, 64);
  }
  __shared__ float red[4][NKF];
  int wv = tid >> 6, lane = tid & 63;
  if (lane == 0) {
    #pragma unroll
    for (int k = 0; k < NKF; ++k) red[wv][k] = p[k];
  }
  __syncthreads();
  if (tid == 0) {
    float o[NKF], mx = -1e30f;
    #pragma unroll
    for (int k = 0; k < NKF; ++k) {
      float t = red[0][k] + red[1][k] + red[2][k] + red[3][k] + b2[k];
      t = (t - m2[k]) * rsqrtf(v2[k] + 1e-5f) * g2[k] + be2[k];
      o[k] = t;
      mx = fmaxf(mx, t);
    }
    float s = 0.f;
    #pragma unroll
    for (int k = 0; k < NKF; ++k) { o[k] = __expf(o[k] - mx); s += o[k]; }
    float inv = 1.f / s;
    #pragma unroll
    for (int k = 0; k < NKF; ++k) wgt[n * NKF + k] = o[k] * inv;
  }
}

// ---------------------------------------------------------------------------
// 5) final: out[n] = RoIAlign(conv(base, sum_k wgt[n,k] K_k)).
//    Block = (roi, 64-ch slice). Stage union window (<=24x24) in LDS as bf16,
//    build 64 smeared 8x8 stencils in LDS, evaluate all samples from LDS,
//    pool in LDS, write contiguous 49-float rows per channel.
__global__ void __launch_bounds__(256, 1) k_final(const unsigned short* __restrict__ featB,
                                                  const float* __restrict__ rois,
                                                  const float* __restrict__ wgt,
                                                  const float* __restrict__ kern,
                                                  float* __restrict__ out) {
  __shared__ __align__(16) unsigned short win[24 * 24 * 64];  // 73728 B
  __shared__ float bmk[64 * 65];                              // 16640 B (pad 65)
  __shared__ __align__(16) float S[64 * 68];                  // 17408 B (pad 68)
  __shared__ float swx[64], swy[64], mk[49];
  __shared__ int srel[64], sw0[2];

  int n = blockIdx.x, c0 = blockIdx.y * 64;
  int tid = threadIdx.x;
  const float* r = rois + n * 5;
  int b = (int)r[0];

  // phase A: per-sample geometry (wave 0) + merged kernel (wave 1)
  if (tid < 64) {
    int gy = tid >> 3, gx = tid & 7;
    float x1 = r[1] * 0.0625f, y1 = r[2] * 0.0625f;
    float x2 = r[3] * 0.0625f, y2 = r[4] * 0.0625f;
    float xs = fminf(fmaxf(x1 + (x2 - x1) * (gx * (1.f / 7.f)), 0.f), 63.f);
    float ys = fminf(fmaxf(y1 + (y2 - y1) * (gy * (1.f / 7.f)), 0.f), 63.f);
    float xf = floorf(xs), yf = floorf(ys);
    int x0 = (int)xf, y0 = (int)yf;
    swx[tid] = xs - xf; swy[tid] = ys - yf;
    int mnx = x0, mny = y0;
    #pragma unroll
    for (int m = 1; m < 64; m <<= 1) {
      mnx = min(mnx, __shfl_xor(mnx, m, 64));
      mny = min(mny, __shfl_xor(mny, m, 64));
    }
    srel[tid] = (y0 - mny) * 24 + (x0 - mnx);
    if (tid == 0) { sw0[0] = mnx; sw0[1] = mny; }
  } else if (tid >= 64 && tid < 64 + 49) {
    int t = tid - 64;
    float m = 0.f;
    #pragma unroll
    for (int k = 0; k < NKF; ++k)
      m += wgt[n * NKF + k] * kern[k * (NC * 49) + t];   // channel-identical
    mk[t] = m;
  }
  __syncthreads();
  int wx0 = sw0[0], wy0 = sw0[1];

  // phase B1: stage window (24x24 cells x 64 ch bf16), clip to padded bounds
  const unsigned short* fb = featB + (size_t)b * (PADW * PADW * NC) + c0;
  #pragma unroll
  for (int it = 0; it < 18; ++it) {
    int idx = tid + it * 256;        // 4608 = 576 cells * 8 ch-groups
    int ch8 = idx & 7;
    int cell = idx >> 3;
    int col = cell % 24, row = cell / 24;
    int gr = wy0 + row, gc = wx0 + col;
    if (gr < PADW && gc < PADW) {
      short8 v = *(const short8*)(fb + ((size_t)gr * PADW + gc) * NC + ch8 * 8);
      *(short8*)(win + cell * 64 + ch8 * 8) = v;
    }
  }
  // phase B2: smear mk (7x7) with per-sample bilinear -> bmk[s][8x8]
  #pragma unroll
  for (int it = 0; it < 16; ++it) {
    int idx = tid + it * 256;        // 4096 = 64 samples * 64 taps
    int s = idx >> 6, e = idx & 63, i = e >> 3, j = e & 7;
    float wxs = swx[s], wys = swy[s];
    float w00 = (1.f - wys) * (1.f - wxs), w01 = (1.f - wys) * wxs;
    float w10 = wys * (1.f - wxs),         w11 = wys * wxs;
    float v = 0.f;
    if (i < 7 && j < 7)   v += w00 * mk[i * 7 + j];
    if (i < 7 && j >= 1)  v += w01 * mk[i * 7 + j - 1];
    if (i >= 1 && j < 7)  v += w10 * mk[(i - 1) * 7 + j];
    if (i >= 1 && j >= 1) v += w11 * mk[(i - 1) * 7 + j - 1];
    bmk[s * 65 + e] = v;
  }
  __syncthreads();

  // phase C: evaluate 64 samples x 64 ch from LDS (thread: 4 samples x 4 ch)
  int c4 = (tid & 15) * 4, sg = tid >> 4;
  #pragma unroll
  for (int t = 0; t < 4; ++t) {
    int s = sg * 4 + t;
    int base = srel[s];
    const float* bw = bmk + s * 65;
    float a0 = 0.f, a1 = 0.f, a2 = 0.f, a3 = 0.f;
    #pragma unroll
    for (int i = 0; i < 8; ++i) {
      #pragma unroll
      for (int j = 0; j < 8; ++j) {
        float w = bw[i * 8 + j];
        uint2 u = *(const uint2*)(win + (base + i * 24 + j) * 64 + c4);
        float v0 = __uint_as_float(u.x << 16);
        float v1 = __uint_as_float(u.x & 0xffff0000u);
        float v2 = __uint_as_float(u.y << 16);
        float v3 = __uint_as_float(u.y & 0xffff0000u);
        a0 += w * v0; a1 += w * v1; a2 += w * v2; a3 += w * v3;
      }
    }
    floatx4 res; res.x = a0; res.y = a1; res.z = a2; res.w = a3;
    *(floatx4*)(S + s * 68 + c4) = res;
  }
  __syncthreads();

  // phase D: 2x2 avg-pool + contiguous store (64 ch x 49)
  for (int it = 0; it < 13; ++it) {
    int idx = tid + it * 256;
    if (idx >= 64 * 49) break;
    int c = idx / 49, pq = idx % 49;
    int p = pq / 7, q = pq % 7;
    int s00 = p * 8 + q;
    float val = 0.25f * (S[s00 * 68 + c] + S[(s00 + 1) * 68 + c]
                         + S[(s00 + 8) * 68 + c] + S[(s00 + 9) * 68 + c]);
    out[((size_t)n * NC + c0 + c) * 49 + pq] = val;
  }
}

// ---------------------------------------------------------------------------
extern "C" void kernel_launch(void* const* d_in, const int* in_sizes, int n_in,
                              void* d_out, int out_size, void* d_ws, size_t ws_size,
                              hipStream_t stream) {
  const float* base = (const float*)d_in[0];
  const float* kern = (const float*)d_in[1];
  const float* rois = (const float*)d_in[2];
  const float* W1  = (const float*)d_in[3];
  const float* b1  = (const float*)d_in[4];
  const float* g1  = (const float*)d_in[5];
  const float* be1 = (const float*)d_in[6];
  const float* m1  = (const float*)d_in[7];
  const float* v1  = (const float*)d_in[8];
  const float* W2  = (const float*)d_in[9];
  const float* b2  = (const float*)d_in[10];
  const float* g2  = (const float*)d_in[11];
  const float* be2 = (const float*)d_in[12];
  const float* m2  = (const float*)d_in[13];
  const float* v2  = (const float*)d_in[14];
  float* out = (float*)d_out;

  // workspace layout (~56 MiB total)
  char* ws = (char*)d_ws;
  const size_t FEATT_BYTES = (size_t)NB * PADW * PADW * NC * 4;   // 10,616,832
  const size_t FEATB_BYTES = (size_t)NB * PADW * PADW * NC * 2;   //  5,308,416
  float*          featT   = (float*)(ws);
  unsigned short* featB   = (unsigned short*)(ws + 10616832);
  unsigned short* xbf     = (unsigned short*)(ws + 15925248);     // 6,422,528
  float*          partial = (float*)(ws + 22347776);              // 33,554,432
  float*          wgt     = (float*)(ws + 55902208);              // 12,288

  hipMemsetAsync(featT, 0, FEATT_BYTES, stream);   // zero halo (conv padding)
  hipMemsetAsync(featB, 0, FEATB_BYTES, stream);
  hipLaunchKernelGGL(k_transpose, dim3(NB * NH), dim3(256), 0, stream, base, featT, featB);
  hipLaunchKernelGGL(k_roi_base, dim3(NROI, 4), dim3(256), 0, stream, featT, rois, xbf);
  hipLaunchKernelGGL(k_gemm1, dim3(64, KCH), dim3(256), 0, stream, xbf, W1, partial);
  hipLaunchKernelGGL(k_reduce_head, dim3(NROI), dim3(256), 0, stream,
                     partial, b1, g1, be1, m1, v1, W2, b2, g2, be2, m2, v2, wgt);
  hipLaunchKernelGGL(k_final, dim3(NROI, 4), dim3(256), 0, stream, featB, rois, wgt, kern, out);
}

// Round 5
// 488.581 us; speedup vs baseline: 2.4139x; 1.0371x over previous
//
#include <hip/hip_runtime.h>

// Problem constants (fixed by reference)
#define NB    2          // batch
#define NC    256        // channels
#define NH    64
#define NW    64
#define PADW  72         // zero-padded spatial dim (3 halo + 8x8 smear window room)
#define NKF   12         // num gaussian kernels
#define NROI  256        // B*R
#define HID   4096
#define INDIM 12544      // 256*49
#define KCH   8          // split-K chunks for GEMM1
#define KCLEN 1568       // 12544/8

typedef __attribute__((ext_vector_type(8))) short short8;
typedef __attribute__((ext_vector_type(4))) float floatx4;

__device__ __forceinline__ unsigned short f2bf(float f) {
  unsigned int u = __float_as_uint(f);
  u += 0x7fffu + ((u >> 16) & 1u);   // round-to-nearest-even
  return (unsigned short)(u >> 16);
}
__device__ __forceinline__ float bf2f(unsigned short s) {
  return __uint_as_float(((unsigned int)s) << 16);
}

// ---------------------------------------------------------------------------
// 1) base_feat [B,C,H,W] -> featB [B,72,72,C] bf16 (3-halo zero-padded).
//    Halo zeroing folded in (d_ws is 0xAA-poisoned before every launch).
__global__ void k_transpose(const float* __restrict__ base,
                            unsigned short* __restrict__ featB) {
  int bid = blockIdx.x;            // B*H = 128
  int b = bid >> 6, y = bid & 63;
  int tid = threadIdx.x;
  __shared__ float tile[64][65];
  for (int cc = 0; cc < 4; ++cc) {
    int c0 = cc * 64;
    #pragma unroll
    for (int i = 0; i < 16; ++i) {
      int idx = tid + i * 256;
      int ci = idx >> 6, xi = idx & 63;
      tile[ci][xi] = base[(((b * NC) + c0 + ci) * NH + y) * NW + xi];
    }
    __syncthreads();
    // write 64 x-positions * 64 ch as packed u32 (2 ch each)
    #pragma unroll
    for (int i = 0; i < 8; ++i) {
      int idx = tid + i * 256;            // 0..2047
      int xo = idx >> 5, cp = idx & 31;   // 32 ch-pairs
      unsigned int lo = f2bf(tile[cp * 2][xo]);
      unsigned int hi = f2bf(tile[cp * 2 + 1][xo]);
      unsigned int pack = lo | (hi << 16);
      size_t o = (((size_t)b * PADW + y + 3) * PADW + xo + 3) * NC + c0 + cp * 2;
      *(unsigned int*)(featB + o) = pack;
    }
    __syncthreads();
  }
  // halo zeroing: 1088 halo px per batch, 64 blocks/batch -> 17 px each
  int hb = bid & 63;
  unsigned int* fz = (unsigned int*)(featB + (size_t)b * (PADW * PADW * NC));
  #pragma unroll
  for (int t = 0; t < 17; ++t) {
    int hidx = hb * 17 + t;               // 0..1087
    int r, c;
    if (hidx < 216)       { r = hidx / 72;            c = hidx % 72; }
    else if (hidx < 576)  { int j = hidx - 216; r = 67 + j / 72; c = j % 72; }
    else                  { int j = hidx - 576; r = 3 + (j >> 3);
                            int k = j & 7; c = (k < 3) ? k : (64 + k); }
    if (tid < 128) fz[((size_t)r * PADW + c) * (NC / 2) + tid] = 0u;
  }
}

// ---------------------------------------------------------------------------
// 2) RoIAlignAvg of base -> MLP input x [NROI, 12544] bf16 (c-major, 7x7 minor)
template<int GY0, int GYN, int P0, int PN, int GX0, int GXN, int Q0, int QN>
__device__ __forceinline__ void roi_base_quad(const unsigned short* __restrict__ featB,
                                              const float* __restrict__ rois,
                                              unsigned short* __restrict__ xbf,
                                              int n, int c) {
  const float* r = rois + n * 5;
  int b = (int)r[0];
  float x1 = r[1] * 0.0625f, y1 = r[2] * 0.0625f;
  float x2 = r[3] * 0.0625f, y2 = r[4] * 0.0625f;
  int ix0[GXN], ix1[GXN], iy0[GYN], iy1[GYN];
  float wx[GXN], wy[GYN];
  #pragma unroll
  for (int i = 0; i < GXN; ++i) {
    float xs = fminf(fmaxf(x1 + (x2 - x1) * ((GX0 + i) * (1.f / 7.f)), 0.f), 63.f);
    float xf = floorf(xs);
    ix0[i] = (int)xf; ix1[i] = min(ix0[i] + 1, 63); wx[i] = xs - xf;
  }
  #pragma unroll
  for (int i = 0; i < GYN; ++i) {
    float ys = fminf(fmaxf(y1 + (y2 - y1) * ((GY0 + i) * (1.f / 7.f)), 0.f), 63.f);
    float yf = floorf(ys);
    iy0[i] = (int)yf; iy1[i] = min(iy0[i] + 1, 63); wy[i] = ys - yf;
  }
  const unsigned short* fb = featB + ((size_t)b * (PADW * PADW) + 3 * PADW + 3) * NC + c;
  float cg[GYN][GXN];
  #pragma unroll
  for (int gy = 0; gy < GYN; ++gy) {
    int r0 = iy0[gy] * (PADW * NC), r1 = iy1[gy] * (PADW * NC);
    #pragma unroll
    for (int gx = 0; gx < GXN; ++gx) {
      int c0 = ix0[gx] * NC, c1 = ix1[gx] * NC;
      float v00 = bf2f(fb[r0 + c0]), v01 = bf2f(fb[r0 + c1]);
      float v10 = bf2f(fb[r1 + c0]), v11 = bf2f(fb[r1 + c1]);
      float top = v00 + (v01 - v00) * wx[gx];
      float bot = v10 + (v11 - v10) * wx[gx];
      cg[gy][gx] = top + (bot - top) * wy[gy];
    }
  }
  unsigned short* xp = xbf + (size_t)n * INDIM + c * 49;
  #pragma unroll
  for (int p = P0; p < P0 + PN; ++p)
    #pragma unroll
    for (int q = Q0; q < Q0 + QN; ++q)
      xp[p * 7 + q] = f2bf(0.25f * (cg[p - GY0][q - GX0] + cg[p - GY0][q - GX0 + 1]
                                    + cg[p - GY0 + 1][q - GX0] + cg[p - GY0 + 1][q - GX0 + 1]));
}

__global__ void __launch_bounds__(256) k_roi_base(const unsigned short* __restrict__ featB,
                                                  const float* __restrict__ rois,
                                                  unsigned short* __restrict__ xbf) {
  int n = blockIdx.x, qd = blockIdx.y, c = threadIdx.x;
  switch (qd) {
    case 0: roi_base_quad<0, 4, 0, 3, 0, 4, 0, 3>(featB, rois, xbf, n, c); break;
    case 1: roi_base_quad<0, 4, 0, 3, 3, 5, 3, 4>(featB, rois, xbf, n, c); break;
    case 2: roi_base_quad<3, 5, 3, 4, 0, 4, 0, 3>(featB, rois, xbf, n, c); break;
    default: roi_base_quad<3, 5, 3, 4, 3, 5, 3, 4>(featB, rois, xbf, n, c); break;
  }
}

// ---------------------------------------------------------------------------
// 3) GEMM1: partial = x @ W1^T, split-K, software-pipelined global prefetch.
__global__ void __launch_bounds__(256) k_gemm1(const unsigned short* __restrict__ A,
                                               const float* __restrict__ W1,
                                               float* __restrict__ partial) {
  __shared__ unsigned short As[256 * 40];
  __shared__ unsigned short Bs[64 * 40];
  int nb = blockIdx.x, kc = blockIdx.y;
  int j0 = nb * 64;
  int kbase = kc * KCLEN;
  int tid = threadIdx.x;
  int wv = tid >> 6, lane = tid & 63;
  int quad = lane >> 4, l15 = lane & 15;
  int m0 = wv * 64;
  floatx4 acc[4][4];
  #pragma unroll
  for (int i = 0; i < 4; ++i)
    #pragma unroll
    for (int j = 0; j < 4; ++j) acc[i][j] = (floatx4)0.0f;

  // per-thread staging pointers
  int arow = tid >> 2, apart = tid & 3;           // A: 4 chunks (rows +64)
  int brow = tid >> 3, bpart = tid & 7;           // B: 2 chunks (rows +32)
  const unsigned short* aptr = A + (size_t)arow * INDIM + kbase + apart * 8;
  const float* bptr = W1 + (size_t)(j0 + brow) * INDIM + kbase + bpart * 4;

  short8 avP[4];
  floatx4 bvP[2];
  #pragma unroll
  for (int rr = 0; rr < 4; ++rr) avP[rr] = *(const short8*)(aptr + (size_t)rr * 64 * INDIM);
  #pragma unroll
  for (int rr = 0; rr < 2; ++rr) bvP[rr] = *(const floatx4*)(bptr + (size_t)rr * 32 * INDIM);

  for (int ks = 0; ks < KCLEN / 32; ++ks) {  // 49 steps
    // write current tile to LDS
    #pragma unroll
    for (int rr = 0; rr < 4; ++rr)
      *(short8*)(As + (arow + rr * 64) * 40 + apart * 8) = avP[rr];
    #pragma unroll
    for (int rr = 0; rr < 2; ++rr) {
      union { unsigned short us[4]; unsigned long long u; } cv;
      cv.us[0] = f2bf(bvP[rr].x); cv.us[1] = f2bf(bvP[rr].y);
      cv.us[2] = f2bf(bvP[rr].z); cv.us[3] = f2bf(bvP[rr].w);
      *(unsigned long long*)(Bs + (brow + rr * 32) * 40 + bpart * 4) = cv.u;
    }
    __syncthreads();
    // prefetch next tile (in flight under the MFMAs)
    if (ks < KCLEN / 32 - 1) {
      int off = (ks + 1) * 32;
      #pragma unroll
      for (int rr = 0; rr < 4; ++rr)
        avP[rr] = *(const short8*)(aptr + (size_t)rr * 64 * INDIM + off);
      #pragma unroll
      for (int rr = 0; rr < 2; ++rr)
        bvP[rr] = *(const floatx4*)(bptr + (size_t)rr * 32 * INDIM + off);
    }
    short8 af[4];
    #pragma unroll
    for (int mi = 0; mi < 4; ++mi)
      af[mi] = *(const short8*)(As + (m0 + mi * 16 + l15) * 40 + quad * 8);
    #pragma unroll
    for (int ni = 0; ni < 4; ++ni) {
      short8 bfv = *(const short8*)(Bs + (ni * 16 + l15) * 40 + quad * 8);
      #pragma unroll
      for (int mi = 0; mi < 4; ++mi)
        acc[mi][ni] = __builtin_amdgcn_mfma_f32_16x16x32_bf16(af[mi], bfv, acc[mi][ni], 0, 0, 0);
    }
    __syncthreads();
  }
  float* po = partial + (size_t)kc * (NROI * HID);
  #pragma unroll
  for (int mi = 0; mi < 4; ++mi) {
    #pragma unroll
    for (int ni = 0; ni < 4; ++ni) {
      int j = j0 + ni * 16 + l15;
      #pragma unroll
      for (int rg = 0; rg < 4; ++rg) {
        int m = m0 + mi * 16 + quad * 4 + rg;
        po[(size_t)m * HID + j] = acc[mi][ni][rg];
      }
    }
  }
}

// ---------------------------------------------------------------------------
// 4) fused: reduce split-K + bias + BN + ReLU + head GEMV + BN + softmax -> wgt
__global__ void __launch_bounds__(256) k_reduce_head(
    const float* __restrict__ partial,
    const float* __restrict__ b1, const float* __restrict__ g1,
    const float* __restrict__ be1, const float* __restrict__ m1,
    const float* __restrict__ v1, const float* __restrict__ W2,
    const float* __restrict__ b2, const float* __restrict__ g2,
    const float* __restrict__ be2, const float* __restrict__ m2,
    const float* __restrict__ v2, float* __restrict__ wgt) {
  int n = blockIdx.x, tid = threadIdx.x;
  float p[NKF];
  #pragma unroll
  for (int k = 0; k < NKF; ++k) p[k] = 0.f;
  #pragma unroll 4
  for (int jj = 0; jj < HID / 256; ++jj) {
    int j = jj * 256 + tid;
    float s = 0.f;
    #pragma unroll
    for (int kc = 0; kc < KCH; ++kc)
      s += partial[(size_t)kc * (NROI * HID) + (size_t)n * HID + j];
    s += b1[j];
    s = (s - m1[j]) * rsqrtf(v1[j] + 1e-5f) * g1[j] + be1[j];
    s = fmaxf(s, 0.f);
    #pragma unroll
    for (int k = 0; k < NKF; ++k) p[k] += s * W2[k * HID + j];
  }
  #pragma unroll
  for (int k = 0; k < NKF; ++k) {
    #pragma unroll
    for (int off = 32; off > 0; off >>= 1) p[k] += __shfl_down(p[k], off, 64);
  }
  __shared__ float red[4][NKF];
  int wv = tid >> 6, lane = tid & 63;
  if (lane == 0) {
    #pragma unroll
    for (int k = 0; k < NKF; ++k) red[wv][k] = p[k];
  }
  __syncthreads();
  if (tid == 0) {
    float o[NKF], mx = -1e30f;
    #pragma unroll
    for (int k = 0; k < NKF; ++k) {
      float t = red[0][k] + red[1][k] + red[2][k] + red[3][k] + b2[k];
      t = (t - m2[k]) * rsqrtf(v2[k] + 1e-5f) * g2[k] + be2[k];
      o[k] = t;
      mx = fmaxf(mx, t);
    }
    float s = 0.f;
    #pragma unroll
    for (int k = 0; k < NKF; ++k) { o[k] = __expf(o[k] - mx); s += o[k]; }
    float inv = 1.f / s;
    #pragma unroll
    for (int k = 0; k < NKF; ++k) wgt[n * NKF + k] = o[k] * inv;
  }
}

// ---------------------------------------------------------------------------
// 5) final: out[n] = RoIAlign(conv(base, sum_k wgt[n,k] K_k)).
//    Block = (roi, 32-ch slice) -> 73 KB LDS, 2 blocks/CU. Each thread: one
//    (sample, 8-ch group): 64 taps of ds_read_b128 + 8 FMA.
__global__ void __launch_bounds__(256, 2) k_final(const unsigned short* __restrict__ featB,
                                                  const float* __restrict__ rois,
                                                  const float* __restrict__ wgt,
                                                  const float* __restrict__ kern,
                                                  float* __restrict__ out) {
  __shared__ __align__(16) unsigned short win[576 * 40];  // 24x24 cells x 32ch (pad 40)
  __shared__ float bmk[64 * 65];                          // 64 samples x 8x8 stencil
  __shared__ __align__(16) float S[64 * 36];              // 64 samples x 32 ch
  __shared__ float swx[64], swy[64], mk[49];
  __shared__ int srel[64], sw0[2];

  int n = blockIdx.x, c0 = blockIdx.y * 32;
  int tid = threadIdx.x;
  const float* r = rois + n * 5;
  int b = (int)r[0];

  // phase A: per-sample geometry (wave 0) + merged kernel (wave 1)
  if (tid < 64) {
    int gy = tid >> 3, gx = tid & 7;
    float x1 = r[1] * 0.0625f, y1 = r[2] * 0.0625f;
    float x2 = r[3] * 0.0625f, y2 = r[4] * 0.0625f;
    float xs = fminf(fmaxf(x1 + (x2 - x1) * (gx * (1.f / 7.f)), 0.f), 63.f);
    float ys = fminf(fmaxf(y1 + (y2 - y1) * (gy * (1.f / 7.f)), 0.f), 63.f);
    float xf = floorf(xs), yf = floorf(ys);
    int x0 = (int)xf, y0 = (int)yf;
    swx[tid] = xs - xf; swy[tid] = ys - yf;
    int mnx = x0, mny = y0;
    #pragma unroll
    for (int m = 1; m < 64; m <<= 1) {
      mnx = min(mnx, __shfl_xor(mnx, m, 64));
      mny = min(mny, __shfl_xor(mny, m, 64));
    }
    srel[tid] = (y0 - mny) * 24 + (x0 - mnx);
    if (tid == 0) { sw0[0] = mnx; sw0[1] = mny; }
  } else if (tid >= 64 && tid < 64 + 49) {
    int t = tid - 64;
    float m = 0.f;
    #pragma unroll
    for (int k = 0; k < NKF; ++k)
      m += wgt[n * NKF + k] * kern[k * (NC * 49) + t];   // channel-identical
    mk[t] = m;
  }
  __syncthreads();
  int wx0 = sw0[0], wy0 = sw0[1];

  // phase B1: stage window (24x24 cells x 32 ch bf16)
  const unsigned short* fb = featB + (size_t)b * (PADW * PADW * NC) + c0;
  #pragma unroll
  for (int it = 0; it < 9; ++it) {
    int idx = tid + it * 256;        // 2304 = 576 cells * 4 ch8-groups
    int g = idx & 3;
    int cell = idx >> 2;
    int col = cell % 24, row = cell / 24;
    int gr = wy0 + row, gc = wx0 + col;
    if (gr < PADW && gc < PADW) {
      short8 v = *(const short8*)(fb + ((size_t)gr * PADW + gc) * NC + g * 8);
      *(short8*)(win + cell * 40 + g * 8) = v;
    }
  }
  // phase B2: smear mk (7x7) with per-sample bilinear -> bmk[s][8x8]
  #pragma unroll
  for (int it = 0; it < 16; ++it) {
    int idx = tid + it * 256;        // 4096 = 64 samples * 64 taps
    int s = idx >> 6, e = idx & 63, i = e >> 3, j = e & 7;
    float wxs = swx[s], wys = swy[s];
    float w00 = (1.f - wys) * (1.f - wxs), w01 = (1.f - wys) * wxs;
    float w10 = wys * (1.f - wxs),         w11 = wys * wxs;
    float v = 0.f;
    if (i < 7 && j < 7)   v += w00 * mk[i * 7 + j];
    if (i < 7 && j >= 1)  v += w01 * mk[i * 7 + j - 1];
    if (i >= 1 && j < 7)  v += w10 * mk[(i - 1) * 7 + j];
    if (i >= 1 && j >= 1) v += w11 * mk[(i - 1) * 7 + j - 1];
    bmk[s * 65 + e] = v;
  }
  __syncthreads();

  // phase C: one (sample, 8-ch group) per thread; 64 taps from LDS
  {
    int s = tid >> 2, g = tid & 3;
    int base = srel[s];
    const float* bw = bmk + s * 65;
    float a0 = 0.f, a1 = 0.f, a2 = 0.f, a3 = 0.f;
    float a4 = 0.f, a5 = 0.f, a6 = 0.f, a7 = 0.f;
    #pragma unroll
    for (int i = 0; i < 8; ++i) {
      #pragma unroll
      for (int j = 0; j < 8; ++j) {
        float w = bw[i * 8 + j];
        uint4 u = *(const uint4*)(win + (base + i * 24 + j) * 40 + g * 8);
        a0 += w * __uint_as_float(u.x << 16);
        a1 += w * __uint_as_float(u.x & 0xffff0000u);
        a2 += w * __uint_as_float(u.y << 16);
        a3 += w * __uint_as_float(u.y & 0xffff0000u);
        a4 += w * __uint_as_float(u.z << 16);
        a5 += w * __uint_as_float(u.z & 0xffff0000u);
        a6 += w * __uint_as_float(u.w << 16);
        a7 += w * __uint_as_float(u.w & 0xffff0000u);
      }
    }
    floatx4 r0; r0.x = a0; r0.y = a1; r0.z = a2; r0.w = a3;
    floatx4 r1; r1.x = a4; r1.y = a5; r1.z = a6; r1.w = a7;
    *(floatx4*)(S + s * 36 + g * 8) = r0;
    *(floatx4*)(S + s * 36 + g * 8 + 4) = r1;
  }
  __syncthreads();

  // phase D: 2x2 avg-pool + contiguous store (32 ch x 49 floats)
  #pragma unroll
  for (int it = 0; it < 7; ++it) {
    int idx = tid + it * 256;
    if (idx < 32 * 49) {
      int c = idx / 49, pq = idx % 49;
      int p = pq / 7, q = pq % 7;
      int s00 = p * 8 + q;
      float val = 0.25f * (S[s00 * 36 + c] + S[(s00 + 1) * 36 + c]
                           + S[(s00 + 8) * 36 + c] + S[(s00 + 9) * 36 + c]);
      out[((size_t)n * NC + c0 + c) * 49 + pq] = val;
    }
  }
}

// ---------------------------------------------------------------------------
extern "C" void kernel_launch(void* const* d_in, const int* in_sizes, int n_in,
                              void* d_out, int out_size, void* d_ws, size_t ws_size,
                              hipStream_t stream) {
  const float* base = (const float*)d_in[0];
  const float* kern = (const float*)d_in[1];
  const float* rois = (const float*)d_in[2];
  const float* W1  = (const float*)d_in[3];
  const float* b1  = (const float*)d_in[4];
  const float* g1  = (const float*)d_in[5];
  const float* be1 = (const float*)d_in[6];
  const float* m1  = (const float*)d_in[7];
  const float* v1  = (const float*)d_in[8];
  const float* W2  = (const float*)d_in[9];
  const float* b2  = (const float*)d_in[10];
  const float* g2  = (const float*)d_in[11];
  const float* be2 = (const float*)d_in[12];
  const float* m2  = (const float*)d_in[13];
  const float* v2  = (const float*)d_in[14];
  float* out = (float*)d_out;

  // workspace layout (~45.3 MiB total)
  char* ws = (char*)d_ws;
  unsigned short* featB   = (unsigned short*)(ws);                // 5,308,416
  unsigned short* xbf     = (unsigned short*)(ws + 5308416);      // 6,422,528
  float*          partial = (float*)(ws + 11730944);              // 33,554,432
  float*          wgt     = (float*)(ws + 45285376);              // 12,288

  hipLaunchKernelGGL(k_transpose, dim3(NB * NH), dim3(256), 0, stream, base, featB);
  hipLaunchKernelGGL(k_roi_base, dim3(NROI, 4), dim3(256), 0, stream, featB, rois, xbf);
  hipLaunchKernelGGL(k_gemm1, dim3(64, KCH), dim3(256), 0, stream, xbf, W1, partial);
  hipLaunchKernelGGL(k_reduce_head, dim3(NROI), dim3(256), 0, stream,
                     partial, b1, g1, be1, m1, v1, W2, b2, g2, be2, m2, v2, wgt);
  hipLaunchKernelGGL(k_final, dim3(NROI, 8), dim3(256), 0, stream, featB, rois, wgt, kern, out);
}